// Round 13
// baseline (561.088 us; speedup 1.0000x reference)
//
#include <hip/hip_runtime.h>
#include <hip/hip_bf16.h>

#define NUM_USERS 100000
#define NUM_ITEMS 50000
#define N_NODES   150000
#define N_EDGES   4000000
#define H         64
#define BATCH     100000
#define MLP_HIDDEN 32
#define NBUCK     586          // ceil(N_NODES / 256); bucket = dst >> 8
#define BCAP      8192         // fixed bucket capacity (mean 6827, sigma 83)

typedef unsigned short ushort_t;

__device__ __forceinline__ float bf2f(ushort_t u) {
    return __uint_as_float(((unsigned)u) << 16);
}
__device__ __forceinline__ ushort_t f2bf(float f) {   // round-to-nearest-even
    unsigned u = __float_as_uint(f);
    u = u + 0x7FFFu + ((u >> 16) & 1u);
    return (ushort_t)(u >> 16);
}
__device__ __forceinline__ float bfLO(unsigned u) { return __uint_as_float(u << 16); }
__device__ __forceinline__ float bfHI(unsigned u) { return __uint_as_float(u & 0xFFFF0000u); }

// ---------------------------------------------------------------------------
// Init: x = concat(ue, ie) fp32  AND  xh = bf16(x).
__global__ __launch_bounds__(256) void init_kernel(const float* __restrict__ ue,
                                                   const float* __restrict__ ie,
                                                   float* __restrict__ x,
                                                   ushort_t* __restrict__ xh) {
    int i = blockIdx.x * 256 + threadIdx.x;        // float4 index, exact grid
    const int UN4 = NUM_USERS * H / 4;
    float4 v = (i < UN4) ? ((const float4*)ue)[i] : ((const float4*)ie)[i - UN4];
    ((float4*)x)[i] = v;
    uint2 p;
    p.x = (unsigned)f2bf(v.x) | ((unsigned)f2bf(v.y) << 16);
    p.y = (unsigned)f2bf(v.z) | ((unsigned)f2bf(v.w) << 16);
    ((uint2*)xh)[i] = p;
}

// ---------------------------------------------------------------------------
// CSR build pass 1: scatter edges into fixed-capacity buckets.
// Entry packed as (src << 8) | (dst & 255).
// SCHUNK=2048: round 12 showed 8192 -> only 489 blocks -> 19% occupancy,
// latency-bound (VALUBusy 1.6%). 1954 blocks ~ 30 waves/CU.
#define SCHUNK 2048
__global__ __launch_bounds__(256) void bucket_scatter_kernel(const int* __restrict__ src,
                                                             const int* __restrict__ dst,
                                                             int* __restrict__ bucketCnt,
                                                             int* __restrict__ ebuf) {
    __shared__ int histL[NBUCK];
    __shared__ int curL[NBUCK];
    int base = blockIdx.x * SCHUNK;
    int end = min(base + SCHUNK, N_EDGES);
    for (int i = threadIdx.x; i < NBUCK; i += 256) histL[i] = 0;
    __syncthreads();
    for (int e = base + threadIdx.x; e < end; e += 256)
        atomicAdd(&histL[dst[e] >> 8], 1);
    __syncthreads();
    for (int b = threadIdx.x; b < NBUCK; b += 256)
        curL[b] = histL[b] ? (b * BCAP + atomicAdd(&bucketCnt[b], histL[b])) : 0;
    __syncthreads();
    for (int e = base + threadIdx.x; e < end; e += 256) {
        int d = dst[e];
        int pos = atomicAdd(&curL[d >> 8], 1);
        ebuf[pos] = (src[e] << 8) | (d & 255);
    }
}

// CSR build pass 2: one block per bucket — local degrees, local scan, fill.
// 512 threads: halves the serial per-block iteration count (round 12: the
// 256-thread version was latency-bound at ~9 waves/CU).
__global__ __launch_bounds__(512) void bucket_build_kernel(const int* __restrict__ ebuf,
                                                           const int* __restrict__ bucketCnt,
                                                           int* __restrict__ deg,
                                                           int* __restrict__ offsets,
                                                           int* __restrict__ csr) {
    __shared__ int degL[256];
    __shared__ int scanL[256];
    __shared__ int curL[256];
    int t = threadIdx.x;
    int b = blockIdx.x;
    int nodeBase = b << 8;
    int start = b * BCAP;
    int cnt = bucketCnt[b];

    if (t < 256) degL[t] = 0;
    __syncthreads();
    for (int i = t; i < cnt; i += 512)
        atomicAdd(&degL[ebuf[start + i] & 255], 1);
    __syncthreads();

    int v = (t < 256) ? degL[t] : 0;
    if (t < 256) scanL[t] = v;
    __syncthreads();
#pragma unroll
    for (int off = 1; off < 256; off <<= 1) {
        int u = (t >= off && t < 256) ? scanL[t - off] : 0;
        __syncthreads();
        if (t < 256) scanL[t] += u;
        __syncthreads();
    }

    if (t < 256) {
        int excl = scanL[t] - v;
        int node = nodeBase + t;
        if (node < N_NODES) {
            deg[node] = v;
            offsets[node] = start + excl;
        }
        curL[t] = excl;
    }
    __syncthreads();

    for (int i = t; i < cnt; i += 512) {
        unsigned p = (unsigned)ebuf[start + i];
        int pos = atomicAdd(&curL[p & 255u], 1);
        csr[start + pos] = (int)(p >> 8);
    }
}

// ---------------------------------------------------------------------------
// Gather-mean over bf16 x: one wave per node, 4 EDGES PER WAVE-INSTRUCTION.
// Lane layout: q = lane>>4 selects edge within quad, fp = lane&15 selects the
// feature quad (4 bf16 = one uint2 load).
__global__ __launch_bounds__(256, 8) void gather_mean_kernel(const ushort_t* __restrict__ xh,
                                                             ushort_t* __restrict__ mean_bf,
                                                             const int* __restrict__ offsets,
                                                             const int* __restrict__ deg,
                                                             const int* __restrict__ csr) {
    int slot = threadIdx.x >> 6;
    int lane = threadIdx.x & 63;
    int q    = lane >> 4;              // edge-in-quad 0..3
    int fp   = lane & 15;              // feature-quad 0..15
    int node = blockIdx.x * 4 + slot;  // N_NODES % 4 == 0

    int base = offsets[node];
    int cnt  = deg[node];
    const uint2* xr = (const uint2*)xh;        // rows of 16 uint2 (64 bf16)

    float a0 = 0.f, a1 = 0.f, a2 = 0.f, a3 = 0.f;

    for (int c = 0; c < cnt; c += 64) {
        int n = min(64, cnt - c);
        int sid = (c + lane < cnt) ? csr[base + c + lane] : 0;
        int nquad = (n + 3) >> 2;
#define PROC(JJ) { int e = 4 * (JJ) + q;                                  \
        int s = __shfl(sid, e, 64);                                       \
        uint2 u = xr[s * 16 + fp];                                        \
        if (c + e >= cnt) { u.x = 0u; u.y = 0u; }                         \
        a0 += bfLO(u.x); a1 += bfHI(u.x); a2 += bfLO(u.y); a3 += bfHI(u.y); }
        int j = 0;
        for (; j + 2 <= nquad; j += 2) { PROC(j) PROC(j + 1) }
        for (; j < nquad; ++j) { PROC(j) }
#undef PROC
    }

    // fold the 4 edge-quad copies: xor-16 then xor-32
    a0 += __shfl_xor(a0, 16, 64); a1 += __shfl_xor(a1, 16, 64);
    a2 += __shfl_xor(a2, 16, 64); a3 += __shfl_xor(a3, 16, 64);
    a0 += __shfl_xor(a0, 32, 64); a1 += __shfl_xor(a1, 32, 64);
    a2 += __shfl_xor(a2, 32, 64); a3 += __shfl_xor(a3, 32, 64);

    if (lane < 16) {
        float rc = 1.0f / fmaxf((float)cnt, 1.0f);
        uint2 p;
        p.x = (unsigned)f2bf(a0 * rc) | ((unsigned)f2bf(a1 * rc) << 16);
        p.y = (unsigned)f2bf(a2 * rc) | ((unsigned)f2bf(a3 * rc) << 16);
        *(uint2*)&mean_bf[node * H + fp * 4] = p;
    }
}

// ---------------------------------------------------------------------------
// Transform: x = relu(mean @ Wl + bl + x @ Wr), IN PLACE; also emits bf16 x.
// 128 nodes/block, 256 threads; thread = 4 nodes x 8 features.
// mean/x staged in LDS as bf16 k-PAIRS transposed; weights f32 in LDS.
__global__ __launch_bounds__(256) void transform_kernel(float* __restrict__ x,
                                                        ushort_t* __restrict__ xh,
                                                        const ushort_t* __restrict__ mean_bf,
                                                        const float* __restrict__ Wl,
                                                        const float* __restrict__ bl,
                                                        const float* __restrict__ Wr,
                                                        int writeBf) {
    __shared__ float    sWl[H * H];        // [k][h] 16 KB
    __shared__ float    sWr[H * H];        // [k][h] 16 KB
    __shared__ unsigned sMT[H / 2][128];   // [kpair][node] bf16x2, 16 KB
    __shared__ unsigned sXT[H / 2][128];   // [kpair][node] bf16x2, 16 KB

    int t = threadIdx.x;
    int node0 = blockIdx.x * 128;

    for (int i = t; i < H * H / 4; i += 256) {
        ((float4*)sWl)[i] = ((const float4*)Wl)[i];
        ((float4*)sWr)[i] = ((const float4*)Wr)[i];
    }
#pragma unroll
    for (int it = 0; it < 8; ++it) {
        int idx = it * 256 + t;
        int n = idx & 127;
        int qd = idx >> 7;                 // float4-quad 0..15 (k = 4q..4q+3)
        int node = node0 + n;
        uint2 mu = make_uint2(0u, 0u);
        uint2 xu = make_uint2(0u, 0u);
        if (node < N_NODES) {
            mu = *(const uint2*)&mean_bf[node * H + qd * 4];
            float4 xv = *(const float4*)&x[node * H + qd * 4];
            xu.x = (unsigned)f2bf(xv.x) | ((unsigned)f2bf(xv.y) << 16);
            xu.y = (unsigned)f2bf(xv.z) | ((unsigned)f2bf(xv.w) << 16);
        }
        sMT[qd * 2][n]     = mu.x;
        sMT[qd * 2 + 1][n] = mu.y;
        sXT[qd * 2][n]     = xu.x;
        sXT[qd * 2 + 1][n] = xu.y;
    }
    __syncthreads();

    int tx = t & 7;                        // feature octet: tx*8 .. tx*8+7
    int ty = t >> 3;                       // node quad 0..31
    int nbase = node0 + ty * 4;

    float acc[4][8];
#pragma unroll
    for (int j = 0; j < 4; ++j)
#pragma unroll
        for (int f = 0; f < 8; ++f) acc[j][f] = 0.0f;

    for (int kp = 0; kp < H / 2; ++kp) {   // k-pairs
        uint4 mu = *(const uint4*)&sMT[kp][ty * 4];   // 4 nodes x {k0,k1}
        uint4 xu = *(const uint4*)&sXT[kp][ty * 4];
        int k0 = kp * 2;
        float4 wl00 = *(const float4*)&sWl[k0 * H + tx * 8];
        float4 wl01 = *(const float4*)&sWl[k0 * H + tx * 8 + 4];
        float4 wr00 = *(const float4*)&sWr[k0 * H + tx * 8];
        float4 wr01 = *(const float4*)&sWr[k0 * H + tx * 8 + 4];
        float4 wl10 = *(const float4*)&sWl[(k0 + 1) * H + tx * 8];
        float4 wl11 = *(const float4*)&sWl[(k0 + 1) * H + tx * 8 + 4];
        float4 wr10 = *(const float4*)&sWr[(k0 + 1) * H + tx * 8];
        float4 wr11 = *(const float4*)&sWr[(k0 + 1) * H + tx * 8 + 4];
        const float wl0[8] = {wl00.x, wl00.y, wl00.z, wl00.w, wl01.x, wl01.y, wl01.z, wl01.w};
        const float wr0[8] = {wr00.x, wr00.y, wr00.z, wr00.w, wr01.x, wr01.y, wr01.z, wr01.w};
        const float wl1[8] = {wl10.x, wl10.y, wl10.z, wl10.w, wl11.x, wl11.y, wl11.z, wl11.w};
        const float wr1[8] = {wr10.x, wr10.y, wr10.z, wr10.w, wr11.x, wr11.y, wr11.z, wr11.w};
        const unsigned mua[4] = {mu.x, mu.y, mu.z, mu.w};
        const unsigned xua[4] = {xu.x, xu.y, xu.z, xu.w};
#pragma unroll
        for (int j = 0; j < 4; ++j) {
            float m0 = bfLO(mua[j]), m1 = bfHI(mua[j]);
            float x0 = bfLO(xua[j]), x1 = bfHI(xua[j]);
#pragma unroll
            for (int f = 0; f < 8; ++f) {
                float a = acc[j][f];
                a = fmaf(m0, wl0[f], a);
                a = fmaf(x0, wr0[f], a);
                a = fmaf(m1, wl1[f], a);
                a = fmaf(x1, wr1[f], a);
                acc[j][f] = a;
            }
        }
    }

    float4 b0 = *(const float4*)&bl[tx * 8];
    float4 b1 = *(const float4*)&bl[tx * 8 + 4];
    const float bias[8] = {b0.x, b0.y, b0.z, b0.w, b1.x, b1.y, b1.z, b1.w};
#pragma unroll
    for (int j = 0; j < 4; ++j) {
        int node = nbase + j;
        if (node < N_NODES) {
            float o[8];
#pragma unroll
            for (int f = 0; f < 8; ++f) o[f] = fmaxf(acc[j][f] + bias[f], 0.0f);
            *(float4*)&x[node * H + tx * 8]     = make_float4(o[0], o[1], o[2], o[3]);
            *(float4*)&x[node * H + tx * 8 + 4] = make_float4(o[4], o[5], o[6], o[7]);
            if (writeBf) {
                uint4 p;
                p.x = (unsigned)f2bf(o[0]) | ((unsigned)f2bf(o[1]) << 16);
                p.y = (unsigned)f2bf(o[2]) | ((unsigned)f2bf(o[3]) << 16);
                p.z = (unsigned)f2bf(o[4]) | ((unsigned)f2bf(o[5]) << 16);
                p.w = (unsigned)f2bf(o[6]) | ((unsigned)f2bf(o[7]) << 16);
                *(uint4*)&xh[node * H + tx * 8] = p;
            }
        }
    }
}

// ---------------------------------------------------------------------------
// Final MLP: rating = clip(relu(pair @ W1 + b1) @ W2 + b2, 1, 5)
__global__ __launch_bounds__(256) void mlp_kernel(const float* __restrict__ x,
                                                  const int* __restrict__ uids,
                                                  const int* __restrict__ iids,
                                                  const float* __restrict__ W1,
                                                  const float* __restrict__ b1,
                                                  const float* __restrict__ W2,
                                                  const float* __restrict__ b2,
                                                  float* __restrict__ out) {
    __shared__ float sW1[2 * H * MLP_HIDDEN];
    __shared__ float sPair[8][2 * H];
    __shared__ float sW2[MLP_HIDDEN];

    for (int i = threadIdx.x; i < 2 * H * MLP_HIDDEN; i += 256) sW1[i] = W1[i];
    if (threadIdx.x < MLP_HIDDEN) sW2[threadIdx.x] = W2[threadIdx.x];

    int slot = threadIdx.x >> 5;
    int j    = threadIdx.x & 31;
    int b = blockIdx.x * 8 + slot;                 // BATCH % 8 == 0

    int u  = uids[b];
    int it = iids[b] + NUM_USERS;
    float2 a = *(const float2*)&x[u * H + j * 2];
    sPair[slot][j * 2]     = a.x;
    sPair[slot][j * 2 + 1] = a.y;
    float2 c = *(const float2*)&x[it * H + j * 2];
    sPair[slot][H + j * 2]     = c.x;
    sPair[slot][H + j * 2 + 1] = c.y;
    __syncthreads();

    float hacc = b1[j];
#pragma unroll
    for (int k = 0; k < 2 * H; ++k)
        hacc = fmaf(sPair[slot][k], sW1[k * MLP_HIDDEN + j], hacc);
    hacc = fmaxf(hacc, 0.0f);

    float r = hacc * sW2[j];
#pragma unroll
    for (int off = 16; off; off >>= 1) r += __shfl_down(r, off, 32);

    if (j == 0) out[b] = fminf(fmaxf(r + b2[0], 1.0f), 5.0f);
}

// ---------------------------------------------------------------------------
extern "C" void kernel_launch(void* const* d_in, const int* in_sizes, int n_in,
                              void* d_out, int out_size, void* d_ws, size_t ws_size,
                              hipStream_t stream) {
    const int*   edge_index = (const int*)d_in[0];
    const int*   user_ids   = (const int*)d_in[1];
    const int*   item_ids   = (const int*)d_in[2];
    const float* user_emb   = (const float*)d_in[3];
    const float* item_emb   = (const float*)d_in[4];
    const float* Wl         = (const float*)d_in[5];
    const float* bl         = (const float*)d_in[6];
    const float* Wr         = (const float*)d_in[7];
    const float* W1         = (const float*)d_in[8];
    const float* b1         = (const float*)d_in[9];
    const float* W2         = (const float*)d_in[10];
    const float* b2         = (const float*)d_in[11];
    float* out = (float*)d_out;

    const int* src = edge_index;
    const int* dst = edge_index + N_EDGES;

    const size_t NH = (size_t)N_NODES * H;
    float* x          = (float*)d_ws;                    // 38.4 MB fp32
    // ebuf region (19.2 MB) doubles as mean_bf after CSR build is done
    int* ebuf         = (int*)(x + NH);                  // NBUCK*BCAP*4 B
    ushort_t* mean_bf = (ushort_t*)ebuf;                 // bf16 overlay
    ushort_t* xh      = (ushort_t*)(ebuf + (size_t)NBUCK * BCAP);  // 19.2 MB bf16
    int* deg          = (int*)(xh + NH);                 // 600 KB
    int* offsets      = deg + N_NODES;                   // 600 KB
    int* bucketCnt    = offsets + N_NODES;               // 2.3 KB
    int* csr          = bucketCnt + NBUCK;               // 19.2 MB (BCAP-strided)

    init_kernel<<<(N_NODES * H / 4) / 256, 256, 0, stream>>>(user_emb, item_emb, x, xh);

    // CSR build: fixed-capacity counting sort (graph identical across layers)
    hipMemsetAsync(bucketCnt, 0, NBUCK * sizeof(int), stream);
    bucket_scatter_kernel<<<(N_EDGES + SCHUNK - 1) / SCHUNK, 256, 0, stream>>>(
        src, dst, bucketCnt, ebuf);
    bucket_build_kernel<<<NBUCK, 512, 0, stream>>>(ebuf, bucketCnt, deg, offsets, csr);

    const int TGRID = (N_NODES + 127) / 128;             // 1172
    for (int l = 0; l < 3; ++l) {
        gather_mean_kernel<<<N_NODES / 4, 256, 0, stream>>>(xh, mean_bf, offsets, deg, csr);
        transform_kernel<<<TGRID, 256, 0, stream>>>(
            x, xh, mean_bf, Wl + (size_t)l * H * H, bl + (size_t)l * H,
            Wr + (size_t)l * H * H, l < 2 ? 1 : 0);
    }

    mlp_kernel<<<BATCH / 8, 256, 0, stream>>>(x, user_ids, item_ids, W1, b1, W2, b2, out);
}

// Round 14
// 501.382 us; speedup vs baseline: 1.1191x; 1.1191x over previous
//
#include <hip/hip_runtime.h>
#include <hip/hip_bf16.h>

#define NUM_USERS 100000
#define NUM_ITEMS 50000
#define N_NODES   150000
#define N_EDGES   4000000
#define H         64
#define BATCH     100000
#define MLP_HIDDEN 32
#define NBUCK     586          // ceil(N_NODES / 256); bucket = dst >> 8
#define BCAP      8192         // fixed bucket capacity (mean 6827, sigma 83)

typedef unsigned short ushort_t;

__device__ __forceinline__ float bf2f(ushort_t u) {
    return __uint_as_float(((unsigned)u) << 16);
}
__device__ __forceinline__ ushort_t f2bf(float f) {   // round-to-nearest-even
    unsigned u = __float_as_uint(f);
    u = u + 0x7FFFu + ((u >> 16) & 1u);
    return (ushort_t)(u >> 16);
}
__device__ __forceinline__ float bfLO(unsigned u) { return __uint_as_float(u << 16); }
__device__ __forceinline__ float bfHI(unsigned u) { return __uint_as_float(u & 0xFFFF0000u); }

// ---------------------------------------------------------------------------
// Init: x = concat(ue, ie) fp32  AND  xh = bf16(x).
__global__ __launch_bounds__(256) void init_kernel(const float* __restrict__ ue,
                                                   const float* __restrict__ ie,
                                                   float* __restrict__ x,
                                                   ushort_t* __restrict__ xh) {
    int i = blockIdx.x * 256 + threadIdx.x;        // float4 index, exact grid
    const int UN4 = NUM_USERS * H / 4;
    float4 v = (i < UN4) ? ((const float4*)ue)[i] : ((const float4*)ie)[i - UN4];
    ((float4*)x)[i] = v;
    uint2 p;
    p.x = (unsigned)f2bf(v.x) | ((unsigned)f2bf(v.y) << 16);
    p.y = (unsigned)f2bf(v.z) | ((unsigned)f2bf(v.w) << 16);
    ((uint2*)xh)[i] = p;
}

// ---------------------------------------------------------------------------
// CSR build pass 1: LDS-SORTED scatter into fixed-capacity buckets.
// Round 13 lesson: the random 4-B writes (64 regions per wave) were the
// bottleneck, not occupancy. Here each chunk is bucket-sorted in LDS first,
// so the write-out is run-coalesced: thread i writes staged[i] to
// ebuf[adjL[buck[i]] + i], consecutive i -> consecutive addresses per run.
// Entry packed as (src << 8) | (dst & 255).
#define SCHUNK 4096
#define SPT    (SCHUNK / 256)          // 16 edges per thread
__global__ __launch_bounds__(256) void bucket_scatter_kernel(const int* __restrict__ src,
                                                             const int* __restrict__ dst,
                                                             int* __restrict__ bucketCnt,
                                                             int* __restrict__ ebuf) {
    __shared__ int      histL[NBUCK];
    __shared__ int      startL[NBUCK];    // local exclusive start of bucket run
    __shared__ int      adjL[NBUCK];      // globalBase - localStart
    __shared__ int      curL[NBUCK];      // staging cursor
    __shared__ unsigned staged[SCHUNK];
    __shared__ ushort_t sbuck[SCHUNK];

    int t = threadIdx.x;
    int base = blockIdx.x * SCHUNK;
    int nst = min(SCHUNK, N_EDGES - base);          // staged count this block

    for (int i = t; i < NBUCK; i += 256) histL[i] = 0;
    __syncthreads();

    // load edges (coalesced) + LDS histogram
    int myd[SPT], mys[SPT];
#pragma unroll
    for (int k = 0; k < SPT; ++k) {
        int e = base + k * 256 + t;
        int d = (e < N_EDGES) ? dst[e] : -1;
        mys[k] = (e < N_EDGES) ? src[e] : 0;
        myd[k] = d;
        if (d >= 0) atomicAdd(&histL[d >> 8], 1);
    }
    __syncthreads();

    // single-wave exclusive scan of histL -> startL
    if (t < 64) {
        const int CH = (NBUCK + 63) / 64;           // 10
        int s0 = t * CH;
        int s1 = min(s0 + CH, NBUCK);
        int s = 0;
        for (int i = s0; i < s1; ++i) s += histL[i];
        int v = s;
#pragma unroll
        for (int off = 1; off < 64; off <<= 1) {
            int u = __shfl_up(v, off, 64);
            if (t >= off) v += u;
        }
        int run = v - s;
        for (int i = s0; i < s1; ++i) {
            startL[i] = run;
            run += histL[i];
        }
    }
    __syncthreads();

    // parallel global reservation per bucket
    for (int b = t; b < NBUCK; b += 256) {
        int h = histL[b];
        int res = h ? (b * BCAP + atomicAdd(&bucketCnt[b], h)) : 0;
        adjL[b] = res - startL[b];
        curL[b] = startL[b];
    }
    __syncthreads();

    // scatter into LDS staging (bucket-sorted order)
#pragma unroll
    for (int k = 0; k < SPT; ++k) {
        int d = myd[k];
        if (d >= 0) {
            int b = d >> 8;
            int pos = atomicAdd(&curL[b], 1);
            staged[pos] = ((unsigned)mys[k] << 8) | (unsigned)(d & 255);
            sbuck[pos] = (ushort_t)b;
        }
    }
    __syncthreads();

    // run-coalesced write-out
    for (int i = t; i < nst; i += 256) {
        int b = sbuck[i];
        ebuf[adjL[b] + i] = (int)staged[i];
    }
}

// CSR build pass 2: one block per bucket — local degrees, local scan, fill.
__global__ __launch_bounds__(512) void bucket_build_kernel(const int* __restrict__ ebuf,
                                                           const int* __restrict__ bucketCnt,
                                                           int* __restrict__ deg,
                                                           int* __restrict__ offsets,
                                                           int* __restrict__ csr) {
    __shared__ int degL[256];
    __shared__ int scanL[256];
    __shared__ int curL[256];
    int t = threadIdx.x;
    int b = blockIdx.x;
    int nodeBase = b << 8;
    int start = b * BCAP;
    int cnt = bucketCnt[b];

    if (t < 256) degL[t] = 0;
    __syncthreads();
    for (int i = t; i < cnt; i += 512)
        atomicAdd(&degL[ebuf[start + i] & 255], 1);
    __syncthreads();

    int v = (t < 256) ? degL[t] : 0;
    if (t < 256) scanL[t] = v;
    __syncthreads();
#pragma unroll
    for (int off = 1; off < 256; off <<= 1) {
        int u = (t >= off && t < 256) ? scanL[t - off] : 0;
        __syncthreads();
        if (t < 256) scanL[t] += u;
        __syncthreads();
    }

    if (t < 256) {
        int excl = scanL[t] - v;
        int node = nodeBase + t;
        if (node < N_NODES) {
            deg[node] = v;
            offsets[node] = start + excl;
        }
        curL[t] = excl;
    }
    __syncthreads();

    for (int i = t; i < cnt; i += 512) {
        unsigned p = (unsigned)ebuf[start + i];
        int pos = atomicAdd(&curL[p & 255u], 1);
        csr[start + pos] = (int)(p >> 8);
    }
}

// ---------------------------------------------------------------------------
// Gather-mean over bf16 x: one wave per node, 4 EDGES PER WAVE-INSTRUCTION.
__global__ __launch_bounds__(256, 8) void gather_mean_kernel(const ushort_t* __restrict__ xh,
                                                             ushort_t* __restrict__ mean_bf,
                                                             const int* __restrict__ offsets,
                                                             const int* __restrict__ deg,
                                                             const int* __restrict__ csr) {
    int slot = threadIdx.x >> 6;
    int lane = threadIdx.x & 63;
    int q    = lane >> 4;              // edge-in-quad 0..3
    int fp   = lane & 15;              // feature-quad 0..15
    int node = blockIdx.x * 4 + slot;  // N_NODES % 4 == 0

    int base = offsets[node];
    int cnt  = deg[node];
    const uint2* xr = (const uint2*)xh;        // rows of 16 uint2 (64 bf16)

    float a0 = 0.f, a1 = 0.f, a2 = 0.f, a3 = 0.f;

    for (int c = 0; c < cnt; c += 64) {
        int n = min(64, cnt - c);
        int sid = (c + lane < cnt) ? csr[base + c + lane] : 0;
        int nquad = (n + 3) >> 2;
#define PROC(JJ) { int e = 4 * (JJ) + q;                                  \
        int s = __shfl(sid, e, 64);                                       \
        uint2 u = xr[s * 16 + fp];                                        \
        if (c + e >= cnt) { u.x = 0u; u.y = 0u; }                         \
        a0 += bfLO(u.x); a1 += bfHI(u.x); a2 += bfLO(u.y); a3 += bfHI(u.y); }
        int j = 0;
        for (; j + 2 <= nquad; j += 2) { PROC(j) PROC(j + 1) }
        for (; j < nquad; ++j) { PROC(j) }
#undef PROC
    }

    // fold the 4 edge-quad copies: xor-16 then xor-32
    a0 += __shfl_xor(a0, 16, 64); a1 += __shfl_xor(a1, 16, 64);
    a2 += __shfl_xor(a2, 16, 64); a3 += __shfl_xor(a3, 16, 64);
    a0 += __shfl_xor(a0, 32, 64); a1 += __shfl_xor(a1, 32, 64);
    a2 += __shfl_xor(a2, 32, 64); a3 += __shfl_xor(a3, 32, 64);

    if (lane < 16) {
        float rc = 1.0f / fmaxf((float)cnt, 1.0f);
        uint2 p;
        p.x = (unsigned)f2bf(a0 * rc) | ((unsigned)f2bf(a1 * rc) << 16);
        p.y = (unsigned)f2bf(a2 * rc) | ((unsigned)f2bf(a3 * rc) << 16);
        *(uint2*)&mean_bf[node * H + fp * 4] = p;
    }
}

// ---------------------------------------------------------------------------
// Transform: x = relu(mean @ Wl + bl + x @ Wr), IN PLACE; also emits bf16 x.
__global__ __launch_bounds__(256) void transform_kernel(float* __restrict__ x,
                                                        ushort_t* __restrict__ xh,
                                                        const ushort_t* __restrict__ mean_bf,
                                                        const float* __restrict__ Wl,
                                                        const float* __restrict__ bl,
                                                        const float* __restrict__ Wr,
                                                        int writeBf) {
    __shared__ float    sWl[H * H];        // [k][h] 16 KB
    __shared__ float    sWr[H * H];        // [k][h] 16 KB
    __shared__ unsigned sMT[H / 2][128];   // [kpair][node] bf16x2, 16 KB
    __shared__ unsigned sXT[H / 2][128];   // [kpair][node] bf16x2, 16 KB

    int t = threadIdx.x;
    int node0 = blockIdx.x * 128;

    for (int i = t; i < H * H / 4; i += 256) {
        ((float4*)sWl)[i] = ((const float4*)Wl)[i];
        ((float4*)sWr)[i] = ((const float4*)Wr)[i];
    }
#pragma unroll
    for (int it = 0; it < 8; ++it) {
        int idx = it * 256 + t;
        int n = idx & 127;
        int qd = idx >> 7;                 // float4-quad 0..15 (k = 4q..4q+3)
        int node = node0 + n;
        uint2 mu = make_uint2(0u, 0u);
        uint2 xu = make_uint2(0u, 0u);
        if (node < N_NODES) {
            mu = *(const uint2*)&mean_bf[node * H + qd * 4];
            float4 xv = *(const float4*)&x[node * H + qd * 4];
            xu.x = (unsigned)f2bf(xv.x) | ((unsigned)f2bf(xv.y) << 16);
            xu.y = (unsigned)f2bf(xv.z) | ((unsigned)f2bf(xv.w) << 16);
        }
        sMT[qd * 2][n]     = mu.x;
        sMT[qd * 2 + 1][n] = mu.y;
        sXT[qd * 2][n]     = xu.x;
        sXT[qd * 2 + 1][n] = xu.y;
    }
    __syncthreads();

    int tx = t & 7;                        // feature octet: tx*8 .. tx*8+7
    int ty = t >> 3;                       // node quad 0..31
    int nbase = node0 + ty * 4;

    float acc[4][8];
#pragma unroll
    for (int j = 0; j < 4; ++j)
#pragma unroll
        for (int f = 0; f < 8; ++f) acc[j][f] = 0.0f;

    for (int kp = 0; kp < H / 2; ++kp) {   // k-pairs
        uint4 mu = *(const uint4*)&sMT[kp][ty * 4];   // 4 nodes x {k0,k1}
        uint4 xu = *(const uint4*)&sXT[kp][ty * 4];
        int k0 = kp * 2;
        float4 wl00 = *(const float4*)&sWl[k0 * H + tx * 8];
        float4 wl01 = *(const float4*)&sWl[k0 * H + tx * 8 + 4];
        float4 wr00 = *(const float4*)&sWr[k0 * H + tx * 8];
        float4 wr01 = *(const float4*)&sWr[k0 * H + tx * 8 + 4];
        float4 wl10 = *(const float4*)&sWl[(k0 + 1) * H + tx * 8];
        float4 wl11 = *(const float4*)&sWl[(k0 + 1) * H + tx * 8 + 4];
        float4 wr10 = *(const float4*)&sWr[(k0 + 1) * H + tx * 8];
        float4 wr11 = *(const float4*)&sWr[(k0 + 1) * H + tx * 8 + 4];
        const float wl0[8] = {wl00.x, wl00.y, wl00.z, wl00.w, wl01.x, wl01.y, wl01.z, wl01.w};
        const float wr0[8] = {wr00.x, wr00.y, wr00.z, wr00.w, wr01.x, wr01.y, wr01.z, wr01.w};
        const float wl1[8] = {wl10.x, wl10.y, wl10.z, wl10.w, wl11.x, wl11.y, wl11.z, wl11.w};
        const float wr1[8] = {wr10.x, wr10.y, wr10.z, wr10.w, wr11.x, wr11.y, wr11.z, wr11.w};
        const unsigned mua[4] = {mu.x, mu.y, mu.z, mu.w};
        const unsigned xua[4] = {xu.x, xu.y, xu.z, xu.w};
#pragma unroll
        for (int j = 0; j < 4; ++j) {
            float m0 = bfLO(mua[j]), m1 = bfHI(mua[j]);
            float x0 = bfLO(xua[j]), x1 = bfHI(xua[j]);
#pragma unroll
            for (int f = 0; f < 8; ++f) {
                float a = acc[j][f];
                a = fmaf(m0, wl0[f], a);
                a = fmaf(x0, wr0[f], a);
                a = fmaf(m1, wl1[f], a);
                a = fmaf(x1, wr1[f], a);
                acc[j][f] = a;
            }
        }
    }

    float4 b0 = *(const float4*)&bl[tx * 8];
    float4 b1 = *(const float4*)&bl[tx * 8 + 4];
    const float bias[8] = {b0.x, b0.y, b0.z, b0.w, b1.x, b1.y, b1.z, b1.w};
#pragma unroll
    for (int j = 0; j < 4; ++j) {
        int node = nbase + j;
        if (node < N_NODES) {
            float o[8];
#pragma unroll
            for (int f = 0; f < 8; ++f) o[f] = fmaxf(acc[j][f] + bias[f], 0.0f);
            *(float4*)&x[node * H + tx * 8]     = make_float4(o[0], o[1], o[2], o[3]);
            *(float4*)&x[node * H + tx * 8 + 4] = make_float4(o[4], o[5], o[6], o[7]);
            if (writeBf) {
                uint4 p;
                p.x = (unsigned)f2bf(o[0]) | ((unsigned)f2bf(o[1]) << 16);
                p.y = (unsigned)f2bf(o[2]) | ((unsigned)f2bf(o[3]) << 16);
                p.z = (unsigned)f2bf(o[4]) | ((unsigned)f2bf(o[5]) << 16);
                p.w = (unsigned)f2bf(o[6]) | ((unsigned)f2bf(o[7]) << 16);
                *(uint4*)&xh[node * H + tx * 8] = p;
            }
        }
    }
}

// ---------------------------------------------------------------------------
// Final MLP: rating = clip(relu(pair @ W1 + b1) @ W2 + b2, 1, 5)
__global__ __launch_bounds__(256) void mlp_kernel(const float* __restrict__ x,
                                                  const int* __restrict__ uids,
                                                  const int* __restrict__ iids,
                                                  const float* __restrict__ W1,
                                                  const float* __restrict__ b1,
                                                  const float* __restrict__ W2,
                                                  const float* __restrict__ b2,
                                                  float* __restrict__ out) {
    __shared__ float sW1[2 * H * MLP_HIDDEN];
    __shared__ float sPair[8][2 * H];
    __shared__ float sW2[MLP_HIDDEN];

    for (int i = threadIdx.x; i < 2 * H * MLP_HIDDEN; i += 256) sW1[i] = W1[i];
    if (threadIdx.x < MLP_HIDDEN) sW2[threadIdx.x] = W2[threadIdx.x];

    int slot = threadIdx.x >> 5;
    int j    = threadIdx.x & 31;
    int b = blockIdx.x * 8 + slot;                 // BATCH % 8 == 0

    int u  = uids[b];
    int it = iids[b] + NUM_USERS;
    float2 a = *(const float2*)&x[u * H + j * 2];
    sPair[slot][j * 2]     = a.x;
    sPair[slot][j * 2 + 1] = a.y;
    float2 c = *(const float2*)&x[it * H + j * 2];
    sPair[slot][H + j * 2]     = c.x;
    sPair[slot][H + j * 2 + 1] = c.y;
    __syncthreads();

    float hacc = b1[j];
#pragma unroll
    for (int k = 0; k < 2 * H; ++k)
        hacc = fmaf(sPair[slot][k], sW1[k * MLP_HIDDEN + j], hacc);
    hacc = fmaxf(hacc, 0.0f);

    float r = hacc * sW2[j];
#pragma unroll
    for (int off = 16; off; off >>= 1) r += __shfl_down(r, off, 32);

    if (j == 0) out[b] = fminf(fmaxf(r + b2[0], 1.0f), 5.0f);
}

// ---------------------------------------------------------------------------
extern "C" void kernel_launch(void* const* d_in, const int* in_sizes, int n_in,
                              void* d_out, int out_size, void* d_ws, size_t ws_size,
                              hipStream_t stream) {
    const int*   edge_index = (const int*)d_in[0];
    const int*   user_ids   = (const int*)d_in[1];
    const int*   item_ids   = (const int*)d_in[2];
    const float* user_emb   = (const float*)d_in[3];
    const float* item_emb   = (const float*)d_in[4];
    const float* Wl         = (const float*)d_in[5];
    const float* bl         = (const float*)d_in[6];
    const float* Wr         = (const float*)d_in[7];
    const float* W1         = (const float*)d_in[8];
    const float* b1         = (const float*)d_in[9];
    const float* W2         = (const float*)d_in[10];
    const float* b2         = (const float*)d_in[11];
    float* out = (float*)d_out;

    const int* src = edge_index;
    const int* dst = edge_index + N_EDGES;

    const size_t NH = (size_t)N_NODES * H;
    float* x          = (float*)d_ws;                    // 38.4 MB fp32
    // ebuf region (19.2 MB) doubles as mean_bf after CSR build is done
    int* ebuf         = (int*)(x + NH);                  // NBUCK*BCAP*4 B
    ushort_t* mean_bf = (ushort_t*)ebuf;                 // bf16 overlay
    ushort_t* xh      = (ushort_t*)(ebuf + (size_t)NBUCK * BCAP);  // 19.2 MB bf16
    int* deg          = (int*)(xh + NH);                 // 600 KB
    int* offsets      = deg + N_NODES;                   // 600 KB
    int* bucketCnt    = offsets + N_NODES;               // 2.3 KB
    int* csr          = bucketCnt + NBUCK;               // 19.2 MB (BCAP-strided)

    init_kernel<<<(N_NODES * H / 4) / 256, 256, 0, stream>>>(user_emb, item_emb, x, xh);

    // CSR build: fixed-capacity counting sort (graph identical across layers)
    hipMemsetAsync(bucketCnt, 0, NBUCK * sizeof(int), stream);
    bucket_scatter_kernel<<<(N_EDGES + SCHUNK - 1) / SCHUNK, 256, 0, stream>>>(
        src, dst, bucketCnt, ebuf);
    bucket_build_kernel<<<NBUCK, 512, 0, stream>>>(ebuf, bucketCnt, deg, offsets, csr);

    const int TGRID = (N_NODES + 127) / 128;             // 1172
    for (int l = 0; l < 3; ++l) {
        gather_mean_kernel<<<N_NODES / 4, 256, 0, stream>>>(xh, mean_bf, offsets, deg, csr);
        transform_kernel<<<TGRID, 256, 0, stream>>>(
            x, xh, mean_bf, Wl + (size_t)l * H * H, bl + (size_t)l * H,
            Wr + (size_t)l * H * H, l < 2 ? 1 : 0);
    }

    mlp_kernel<<<BATCH / 8, 256, 0, stream>>>(x, user_ids, item_ids, W1, b1, W2, b2, out);
}

// Round 15
// 489.863 us; speedup vs baseline: 1.1454x; 1.0235x over previous
//
#include <hip/hip_runtime.h>
#include <hip/hip_bf16.h>

#define NUM_USERS 100000
#define NUM_ITEMS 50000
#define N_NODES   150000
#define N_EDGES   4000000
#define H         64
#define BATCH     100000
#define MLP_HIDDEN 32
#define NBUCK     586          // ceil(N_NODES / 256); bucket = dst >> 8
#define BCAP      8192         // fixed bucket capacity (padded total <= ~7900)
#define ZROW      N_NODES      // index of the all-zero row appended to xh

typedef unsigned short ushort_t;
typedef float f32x2 __attribute__((ext_vector_type(2)));

__device__ __forceinline__ ushort_t f2bf(float f) {   // round-to-nearest-even
    unsigned u = __float_as_uint(f);
    u = u + 0x7FFFu + ((u >> 16) & 1u);
    return (ushort_t)(u >> 16);
}
__device__ __forceinline__ float bfLO(unsigned u) { return __uint_as_float(u << 16); }
__device__ __forceinline__ float bfHI(unsigned u) { return __uint_as_float(u & 0xFFFF0000u); }

// ---------------------------------------------------------------------------
// Init: xh = bf16(concat(ue, ie)).  (fp32 x buffer eliminated this round.)
__global__ __launch_bounds__(256) void init_kernel(const float* __restrict__ ue,
                                                   const float* __restrict__ ie,
                                                   ushort_t* __restrict__ xh) {
    int i = blockIdx.x * 256 + threadIdx.x;        // float4 index, exact grid
    const int UN4 = NUM_USERS * H / 4;
    float4 v = (i < UN4) ? ((const float4*)ue)[i] : ((const float4*)ie)[i - UN4];
    uint2 p;
    p.x = (unsigned)f2bf(v.x) | ((unsigned)f2bf(v.y) << 16);
    p.y = (unsigned)f2bf(v.z) | ((unsigned)f2bf(v.w) << 16);
    ((uint2*)xh)[i] = p;
}

// ---------------------------------------------------------------------------
// CSR build pass 1: LDS-SORTED scatter into fixed-capacity buckets (round 14,
// proven). Entry packed as (src << 8) | (dst & 255).
#define SCHUNK 4096
#define SPT    (SCHUNK / 256)          // 16 edges per thread
__global__ __launch_bounds__(256) void bucket_scatter_kernel(const int* __restrict__ src,
                                                             const int* __restrict__ dst,
                                                             int* __restrict__ bucketCnt,
                                                             int* __restrict__ ebuf) {
    __shared__ int      histL[NBUCK];
    __shared__ int      startL[NBUCK];
    __shared__ int      adjL[NBUCK];
    __shared__ int      curL[NBUCK];
    __shared__ unsigned staged[SCHUNK];
    __shared__ ushort_t sbuck[SCHUNK];

    int t = threadIdx.x;
    int base = blockIdx.x * SCHUNK;
    int nst = min(SCHUNK, N_EDGES - base);

    for (int i = t; i < NBUCK; i += 256) histL[i] = 0;
    __syncthreads();

    int myd[SPT], mys[SPT];
#pragma unroll
    for (int k = 0; k < SPT; ++k) {
        int e = base + k * 256 + t;
        int d = (e < N_EDGES) ? dst[e] : -1;
        mys[k] = (e < N_EDGES) ? src[e] : 0;
        myd[k] = d;
        if (d >= 0) atomicAdd(&histL[d >> 8], 1);
    }
    __syncthreads();

    if (t < 64) {
        const int CH = (NBUCK + 63) / 64;
        int s0 = t * CH;
        int s1 = min(s0 + CH, NBUCK);
        int s = 0;
        for (int i = s0; i < s1; ++i) s += histL[i];
        int v = s;
#pragma unroll
        for (int off = 1; off < 64; off <<= 1) {
            int u = __shfl_up(v, off, 64);
            if (t >= off) v += u;
        }
        int run = v - s;
        for (int i = s0; i < s1; ++i) {
            startL[i] = run;
            run += histL[i];
        }
    }
    __syncthreads();

    for (int b = t; b < NBUCK; b += 256) {
        int h = histL[b];
        int res = h ? (b * BCAP + atomicAdd(&bucketCnt[b], h)) : 0;
        adjL[b] = res - startL[b];
        curL[b] = startL[b];
    }
    __syncthreads();

#pragma unroll
    for (int k = 0; k < SPT; ++k) {
        int d = myd[k];
        if (d >= 0) {
            int b = d >> 8;
            int pos = atomicAdd(&curL[b], 1);
            staged[pos] = ((unsigned)mys[k] << 8) | (unsigned)(d & 255);
            sbuck[pos] = (ushort_t)b;
        }
    }
    __syncthreads();

    for (int i = t; i < nst; i += 256) {
        int b = sbuck[i];
        ebuf[adjL[b] + i] = (int)staged[i];
    }
}

// CSR build pass 2: one block per bucket. Node segments PADDED to a multiple
// of 4 with ZROW entries so the gather needs no per-quad tail masking.
__global__ __launch_bounds__(512) void bucket_build_kernel(const int* __restrict__ ebuf,
                                                           const int* __restrict__ bucketCnt,
                                                           int* __restrict__ deg,
                                                           int* __restrict__ offsets,
                                                           int* __restrict__ csr) {
    __shared__ int degL[256];
    __shared__ int scanL[256];
    __shared__ int curL[256];
    int t = threadIdx.x;
    int b = blockIdx.x;
    int nodeBase = b << 8;
    int start = b * BCAP;
    int cnt = bucketCnt[b];

    if (t < 256) degL[t] = 0;
    __syncthreads();
    for (int i = t; i < cnt; i += 512)
        atomicAdd(&degL[ebuf[start + i] & 255], 1);
    __syncthreads();

    int v  = (t < 256) ? degL[t] : 0;
    int vp = (v + 3) & ~3;                 // padded degree
    if (t < 256) scanL[t] = vp;
    __syncthreads();
#pragma unroll
    for (int off = 1; off < 256; off <<= 1) {
        int u = (t >= off && t < 256) ? scanL[t - off] : 0;
        __syncthreads();
        if (t < 256) scanL[t] += u;
        __syncthreads();
    }

    int excl = 0;
    if (t < 256) {
        excl = scanL[t] - vp;
        int node = nodeBase + t;
        if (node < N_NODES) {
            deg[node] = v;
            offsets[node] = start + excl;
        }
        curL[t] = excl;
    }
    __syncthreads();

    for (int i = t; i < cnt; i += 512) {
        unsigned p = (unsigned)ebuf[start + i];
        int pos = atomicAdd(&curL[p & 255u], 1);
        csr[start + pos] = (int)(p >> 8);
    }
    __syncthreads();

    // pad each node's segment [excl+v, excl+vp) with the zero row
    if (t < 256) {
        for (int i = excl + v; i < excl + vp; ++i) csr[start + i] = ZROW;
    }
}

// ---------------------------------------------------------------------------
// Gather-mean over bf16 x: one wave per node, 4 edges per wave-instruction,
// NO per-quad masking (segments padded with ZROW -> adds 0.0).
__global__ __launch_bounds__(256, 8) void gather_mean_kernel(const ushort_t* __restrict__ xh,
                                                             ushort_t* __restrict__ mean_bf,
                                                             const int* __restrict__ offsets,
                                                             const int* __restrict__ deg,
                                                             const int* __restrict__ csr) {
    int slot = threadIdx.x >> 6;
    int lane = threadIdx.x & 63;
    int q    = lane >> 4;              // edge-in-quad 0..3
    int fp   = lane & 15;              // feature-quad 0..15
    int node = blockIdx.x * 4 + slot;  // N_NODES % 4 == 0

    int base = offsets[node];
    int cnt  = deg[node];
    int cnt4 = (cnt + 3) & ~3;
    const uint2* xr = (const uint2*)xh;        // rows of 16 uint2 (64 bf16)

    float a0 = 0.f, a1 = 0.f, a2 = 0.f, a3 = 0.f;

    for (int c = 0; c < cnt4; c += 64) {
        int rem = cnt4 - c;                    // multiple of 4
        int sid = (lane < rem) ? csr[base + c + lane] : ZROW;
        int nq = min(64, rem) >> 2;
#define PROC(JJ) { int s = __shfl(sid, 4 * (JJ) + q, 64);                 \
        uint2 u = xr[s * 16 + fp];                                        \
        a0 += bfLO(u.x); a1 += bfHI(u.x); a2 += bfLO(u.y); a3 += bfHI(u.y); }
        int j = 0;
        for (; j + 2 <= nq; j += 2) { PROC(j) PROC(j + 1) }
        for (; j < nq; ++j) { PROC(j) }
#undef PROC
    }

    // fold the 4 edge-quad copies: xor-16 then xor-32
    a0 += __shfl_xor(a0, 16, 64); a1 += __shfl_xor(a1, 16, 64);
    a2 += __shfl_xor(a2, 16, 64); a3 += __shfl_xor(a3, 16, 64);
    a0 += __shfl_xor(a0, 32, 64); a1 += __shfl_xor(a1, 32, 64);
    a2 += __shfl_xor(a2, 32, 64); a3 += __shfl_xor(a3, 32, 64);

    if (lane < 16) {
        float rc = 1.0f / fmaxf((float)cnt, 1.0f);
        uint2 p;
        p.x = (unsigned)f2bf(a0 * rc) | ((unsigned)f2bf(a1 * rc) << 16);
        p.y = (unsigned)f2bf(a2 * rc) | ((unsigned)f2bf(a3 * rc) << 16);
        *(uint2*)&mean_bf[node * H + fp * 4] = p;
    }
}

// ---------------------------------------------------------------------------
// Transform: xh = bf16(relu(mean @ Wl + bl + x @ Wr)), fully bf16 dataflow,
// IN PLACE on xh (block reads only its own rows, barrier, then writes).
// f32x2 accumulators via __builtin_elementwise_fma -> v_pk_fma_f32.
__global__ __launch_bounds__(256) void transform_kernel(ushort_t* __restrict__ xh,
                                                        const ushort_t* __restrict__ mean_bf,
                                                        const float* __restrict__ Wl,
                                                        const float* __restrict__ bl,
                                                        const float* __restrict__ Wr) {
    __shared__ float    sWl[H * H];        // [k][h] 16 KB
    __shared__ float    sWr[H * H];        // [k][h] 16 KB
    __shared__ unsigned sMT[H / 2][128];   // [kpair][node] bf16x2, 16 KB
    __shared__ unsigned sXT[H / 2][128];   // [kpair][node] bf16x2, 16 KB

    int t = threadIdx.x;
    int node0 = blockIdx.x * 128;

    for (int i = t; i < H * H / 4; i += 256) {
        ((float4*)sWl)[i] = ((const float4*)Wl)[i];
        ((float4*)sWr)[i] = ((const float4*)Wr)[i];
    }
#pragma unroll
    for (int it = 0; it < 8; ++it) {
        int idx = it * 256 + t;
        int n = idx & 127;
        int qd = idx >> 7;                 // uint2-quad 0..15 (k = 4qd..4qd+3)
        int node = node0 + n;
        uint2 mu = make_uint2(0u, 0u);
        uint2 xu = make_uint2(0u, 0u);
        if (node < N_NODES) {
            mu = *(const uint2*)&mean_bf[node * H + qd * 4];
            xu = *(const uint2*)&xh[node * H + qd * 4];
        }
        sMT[qd * 2][n]     = mu.x;
        sMT[qd * 2 + 1][n] = mu.y;
        sXT[qd * 2][n]     = xu.x;
        sXT[qd * 2 + 1][n] = xu.y;
    }
    __syncthreads();

    int tx = t & 7;                        // feature octet: tx*8 .. tx*8+7
    int ty = t >> 3;                       // node quad 0..31
    int nbase = node0 + ty * 4;

    f32x2 acc[4][4];                       // [node][feature-pair]
#pragma unroll
    for (int j = 0; j < 4; ++j)
#pragma unroll
        for (int p = 0; p < 4; ++p) acc[j][p] = (f32x2)(0.0f);

    for (int kp = 0; kp < H / 2; ++kp) {   // k-pairs
        uint4 mu = *(const uint4*)&sMT[kp][ty * 4];   // 4 nodes x {k0,k1}
        uint4 xu = *(const uint4*)&sXT[kp][ty * 4];
        int k0 = kp * 2;
        float4 wl00 = *(const float4*)&sWl[k0 * H + tx * 8];
        float4 wl01 = *(const float4*)&sWl[k0 * H + tx * 8 + 4];
        float4 wr00 = *(const float4*)&sWr[k0 * H + tx * 8];
        float4 wr01 = *(const float4*)&sWr[k0 * H + tx * 8 + 4];
        float4 wl10 = *(const float4*)&sWl[(k0 + 1) * H + tx * 8];
        float4 wl11 = *(const float4*)&sWl[(k0 + 1) * H + tx * 8 + 4];
        float4 wr10 = *(const float4*)&sWr[(k0 + 1) * H + tx * 8];
        float4 wr11 = *(const float4*)&sWr[(k0 + 1) * H + tx * 8 + 4];
        f32x2 wl0p[4] = {{wl00.x, wl00.y}, {wl00.z, wl00.w}, {wl01.x, wl01.y}, {wl01.z, wl01.w}};
        f32x2 wr0p[4] = {{wr00.x, wr00.y}, {wr00.z, wr00.w}, {wr01.x, wr01.y}, {wr01.z, wr01.w}};
        f32x2 wl1p[4] = {{wl10.x, wl10.y}, {wl10.z, wl10.w}, {wl11.x, wl11.y}, {wl11.z, wl11.w}};
        f32x2 wr1p[4] = {{wr10.x, wr10.y}, {wr10.z, wr10.w}, {wr11.x, wr11.y}, {wr11.z, wr11.w}};
        const unsigned mua[4] = {mu.x, mu.y, mu.z, mu.w};
        const unsigned xua[4] = {xu.x, xu.y, xu.z, xu.w};
#pragma unroll
        for (int j = 0; j < 4; ++j) {
            f32x2 m0 = (f32x2)(bfLO(mua[j]));
            f32x2 m1 = (f32x2)(bfHI(mua[j]));
            f32x2 x0 = (f32x2)(bfLO(xua[j]));
            f32x2 x1 = (f32x2)(bfHI(xua[j]));
#pragma unroll
            for (int p = 0; p < 4; ++p) {
                f32x2 a = acc[j][p];
                a = __builtin_elementwise_fma(m0, wl0p[p], a);
                a = __builtin_elementwise_fma(x0, wr0p[p], a);
                a = __builtin_elementwise_fma(m1, wl1p[p], a);
                a = __builtin_elementwise_fma(x1, wr1p[p], a);
                acc[j][p] = a;
            }
        }
    }

    float4 b0 = *(const float4*)&bl[tx * 8];
    float4 b1 = *(const float4*)&bl[tx * 8 + 4];
    f32x2 bias[4] = {{b0.x, b0.y}, {b0.z, b0.w}, {b1.x, b1.y}, {b1.z, b1.w}};
#pragma unroll
    for (int j = 0; j < 4; ++j) {
        int node = nbase + j;
        if (node < N_NODES) {
            uint4 pk;
            unsigned w[4];
#pragma unroll
            for (int p = 0; p < 4; ++p) {
                float o0 = fmaxf(acc[j][p].x + bias[p].x, 0.0f);
                float o1 = fmaxf(acc[j][p].y + bias[p].y, 0.0f);
                w[p] = (unsigned)f2bf(o0) | ((unsigned)f2bf(o1) << 16);
            }
            pk.x = w[0]; pk.y = w[1]; pk.z = w[2]; pk.w = w[3];
            *(uint4*)&xh[node * H + tx * 8] = pk;
        }
    }
}

// ---------------------------------------------------------------------------
// Final MLP (bf16 feature reads): rating = clip(relu(pair@W1+b1)@W2+b2, 1, 5)
__global__ __launch_bounds__(256) void mlp_kernel(const ushort_t* __restrict__ xh,
                                                  const int* __restrict__ uids,
                                                  const int* __restrict__ iids,
                                                  const float* __restrict__ W1,
                                                  const float* __restrict__ b1,
                                                  const float* __restrict__ W2,
                                                  const float* __restrict__ b2,
                                                  float* __restrict__ out) {
    __shared__ float sW1[2 * H * MLP_HIDDEN];
    __shared__ float sPair[8][2 * H];
    __shared__ float sW2[MLP_HIDDEN];

    for (int i = threadIdx.x; i < 2 * H * MLP_HIDDEN; i += 256) sW1[i] = W1[i];
    if (threadIdx.x < MLP_HIDDEN) sW2[threadIdx.x] = W2[threadIdx.x];

    int slot = threadIdx.x >> 5;
    int j    = threadIdx.x & 31;
    int b = blockIdx.x * 8 + slot;                 // BATCH % 8 == 0

    int u  = uids[b];
    int it = iids[b] + NUM_USERS;
    const uint2* xr = (const uint2*)xh;
    uint2 v = (j < 16) ? xr[u * 16 + j] : xr[it * 16 + (j - 16)];
    int off = (j < 16) ? j * 4 : (H + (j - 16) * 4);
    sPair[slot][off + 0] = bfLO(v.x);
    sPair[slot][off + 1] = bfHI(v.x);
    sPair[slot][off + 2] = bfLO(v.y);
    sPair[slot][off + 3] = bfHI(v.y);
    __syncthreads();

    float hacc = b1[j];
#pragma unroll
    for (int k = 0; k < 2 * H; ++k)
        hacc = fmaf(sPair[slot][k], sW1[k * MLP_HIDDEN + j], hacc);
    hacc = fmaxf(hacc, 0.0f);

    float r = hacc * sW2[j];
#pragma unroll
    for (int off2 = 16; off2; off2 >>= 1) r += __shfl_down(r, off2, 32);

    if (j == 0) out[b] = fminf(fmaxf(r + b2[0], 1.0f), 5.0f);
}

// ---------------------------------------------------------------------------
extern "C" void kernel_launch(void* const* d_in, const int* in_sizes, int n_in,
                              void* d_out, int out_size, void* d_ws, size_t ws_size,
                              hipStream_t stream) {
    const int*   edge_index = (const int*)d_in[0];
    const int*   user_ids   = (const int*)d_in[1];
    const int*   item_ids   = (const int*)d_in[2];
    const float* user_emb   = (const float*)d_in[3];
    const float* item_emb   = (const float*)d_in[4];
    const float* Wl         = (const float*)d_in[5];
    const float* bl         = (const float*)d_in[6];
    const float* Wr         = (const float*)d_in[7];
    const float* W1         = (const float*)d_in[8];
    const float* b1         = (const float*)d_in[9];
    const float* W2         = (const float*)d_in[10];
    const float* b2         = (const float*)d_in[11];
    float* out = (float*)d_out;

    const int* src = edge_index;
    const int* dst = edge_index + N_EDGES;

    const size_t NH = (size_t)N_NODES * H;
    ushort_t* xh      = (ushort_t*)d_ws;                 // (N_NODES+1) bf16 rows
    int* ebuf         = (int*)(xh + NH + H);             // 19.2 MB
    ushort_t* mean_bf = (ushort_t*)ebuf;                 // bf16 overlay (fits)
    int* deg          = ebuf + (size_t)NBUCK * BCAP;     // 600 KB
    int* offsets      = deg + N_NODES;                   // 600 KB
    int* bucketCnt    = offsets + N_NODES;               // 2.3 KB
    int* csr          = bucketCnt + NBUCK;               // 19.2 MB (BCAP-strided)

    init_kernel<<<(N_NODES * H / 4) / 256, 256, 0, stream>>>(user_emb, item_emb, xh);
    hipMemsetAsync(xh + NH, 0, H * sizeof(ushort_t), stream);   // zero row (ZROW)

    // CSR build: fixed-capacity counting sort (graph identical across layers)
    hipMemsetAsync(bucketCnt, 0, NBUCK * sizeof(int), stream);
    bucket_scatter_kernel<<<(N_EDGES + SCHUNK - 1) / SCHUNK, 256, 0, stream>>>(
        src, dst, bucketCnt, ebuf);
    bucket_build_kernel<<<NBUCK, 512, 0, stream>>>(ebuf, bucketCnt, deg, offsets, csr);

    const int TGRID = (N_NODES + 127) / 128;             // 1172
    for (int l = 0; l < 3; ++l) {
        gather_mean_kernel<<<N_NODES / 4, 256, 0, stream>>>(xh, mean_bf, offsets, deg, csr);
        transform_kernel<<<TGRID, 256, 0, stream>>>(
            xh, mean_bf, Wl + (size_t)l * H * H, bl + (size_t)l * H,
            Wr + (size_t)l * H * H);
    }

    mlp_kernel<<<BATCH / 8, 256, 0, stream>>>(xh, user_ids, item_ids, W1, b1, W2, b2, out);
}

// Round 16
// 487.541 us; speedup vs baseline: 1.1509x; 1.0048x over previous
//
#include <hip/hip_runtime.h>
#include <hip/hip_bf16.h>

#define NUM_USERS 100000
#define NUM_ITEMS 50000
#define N_NODES   150000
#define N_EDGES   4000000
#define H         64
#define BATCH     100000
#define MLP_HIDDEN 32
#define NBUCK     586          // ceil(N_NODES / 256); bucket = dst >> 8
#define BCAP      8192         // fixed bucket capacity (padded total <= ~7900)
#define ZROW      N_NODES      // index of the all-zero row appended to xh

typedef unsigned short ushort_t;
typedef float f32x2 __attribute__((ext_vector_type(2)));

__device__ __forceinline__ ushort_t f2bf(float f) {   // round-to-nearest-even
    unsigned u = __float_as_uint(f);
    u = u + 0x7FFFu + ((u >> 16) & 1u);
    return (ushort_t)(u >> 16);
}
__device__ __forceinline__ unsigned pk2bf(float a, float b) {
    return (unsigned)f2bf(a) | ((unsigned)f2bf(b) << 16);
}
__device__ __forceinline__ float bfLO(unsigned u) { return __uint_as_float(u << 16); }
__device__ __forceinline__ float bfHI(unsigned u) { return __uint_as_float(u & 0xFFFF0000u); }

// ---------------------------------------------------------------------------
// Init: xh = bf16(concat(ue, ie)).
__global__ __launch_bounds__(256) void init_kernel(const float* __restrict__ ue,
                                                   const float* __restrict__ ie,
                                                   ushort_t* __restrict__ xh) {
    int i = blockIdx.x * 256 + threadIdx.x;        // float4 index, exact grid
    const int UN4 = NUM_USERS * H / 4;
    float4 v = (i < UN4) ? ((const float4*)ue)[i] : ((const float4*)ie)[i - UN4];
    uint2 p;
    p.x = pk2bf(v.x, v.y);
    p.y = pk2bf(v.z, v.w);
    ((uint2*)xh)[i] = p;
}

// ---------------------------------------------------------------------------
// CSR build pass 1: LDS-SORTED scatter into fixed-capacity buckets (proven).
// Entry packed as (src << 8) | (dst & 255).
#define SCHUNK 4096
#define SPT    (SCHUNK / 256)          // 16 edges per thread
__global__ __launch_bounds__(256) void bucket_scatter_kernel(const int* __restrict__ src,
                                                             const int* __restrict__ dst,
                                                             int* __restrict__ bucketCnt,
                                                             int* __restrict__ ebuf) {
    __shared__ int      histL[NBUCK];
    __shared__ int      startL[NBUCK];
    __shared__ int      adjL[NBUCK];
    __shared__ int      curL[NBUCK];
    __shared__ unsigned staged[SCHUNK];
    __shared__ ushort_t sbuck[SCHUNK];

    int t = threadIdx.x;
    int base = blockIdx.x * SCHUNK;
    int nst = min(SCHUNK, N_EDGES - base);

    for (int i = t; i < NBUCK; i += 256) histL[i] = 0;
    __syncthreads();

    int myd[SPT], mys[SPT];
#pragma unroll
    for (int k = 0; k < SPT; ++k) {
        int e = base + k * 256 + t;
        int d = (e < N_EDGES) ? dst[e] : -1;
        mys[k] = (e < N_EDGES) ? src[e] : 0;
        myd[k] = d;
        if (d >= 0) atomicAdd(&histL[d >> 8], 1);
    }
    __syncthreads();

    if (t < 64) {
        const int CH = (NBUCK + 63) / 64;
        int s0 = t * CH;
        int s1 = min(s0 + CH, NBUCK);
        int s = 0;
        for (int i = s0; i < s1; ++i) s += histL[i];
        int v = s;
#pragma unroll
        for (int off = 1; off < 64; off <<= 1) {
            int u = __shfl_up(v, off, 64);
            if (t >= off) v += u;
        }
        int run = v - s;
        for (int i = s0; i < s1; ++i) {
            startL[i] = run;
            run += histL[i];
        }
    }
    __syncthreads();

    for (int b = t; b < NBUCK; b += 256) {
        int h = histL[b];
        int res = h ? (b * BCAP + atomicAdd(&bucketCnt[b], h)) : 0;
        adjL[b] = res - startL[b];
        curL[b] = startL[b];
    }
    __syncthreads();

#pragma unroll
    for (int k = 0; k < SPT; ++k) {
        int d = myd[k];
        if (d >= 0) {
            int b = d >> 8;
            int pos = atomicAdd(&curL[b], 1);
            staged[pos] = ((unsigned)mys[k] << 8) | (unsigned)(d & 255);
            sbuck[pos] = (ushort_t)b;
        }
    }
    __syncthreads();

    for (int i = t; i < nst; i += 256) {
        int b = sbuck[i];
        ebuf[adjL[b] + i] = (int)staged[i];
    }
}

// CSR build pass 2: one block per bucket; segments padded to multiple of 4
// with ZROW. 1024 threads (round 15's 512 was latency-bound on serial iters).
__global__ __launch_bounds__(1024) void bucket_build_kernel(const int* __restrict__ ebuf,
                                                            const int* __restrict__ bucketCnt,
                                                            int* __restrict__ deg,
                                                            int* __restrict__ offsets,
                                                            int* __restrict__ csr) {
    __shared__ int degL[256];
    __shared__ int scanL[256];
    __shared__ int curL[256];
    int t = threadIdx.x;
    int b = blockIdx.x;
    int nodeBase = b << 8;
    int start = b * BCAP;
    int cnt = bucketCnt[b];

    if (t < 256) degL[t] = 0;
    __syncthreads();
    for (int i = t; i < cnt; i += 1024)
        atomicAdd(&degL[ebuf[start + i] & 255], 1);
    __syncthreads();

    int v  = (t < 256) ? degL[t] : 0;
    int vp = (v + 3) & ~3;                 // padded degree
    if (t < 256) scanL[t] = vp;
    __syncthreads();
#pragma unroll
    for (int off = 1; off < 256; off <<= 1) {
        int u = (t >= off && t < 256) ? scanL[t - off] : 0;
        __syncthreads();
        if (t < 256) scanL[t] += u;
        __syncthreads();
    }

    int excl = 0;
    if (t < 256) {
        excl = scanL[t] - vp;
        int node = nodeBase + t;
        if (node < N_NODES) {
            deg[node] = v;
            offsets[node] = start + excl;
        }
        curL[t] = excl;
    }
    __syncthreads();

    for (int i = t; i < cnt; i += 1024) {
        unsigned p = (unsigned)ebuf[start + i];
        int pos = atomicAdd(&curL[p & 255u], 1);
        csr[start + pos] = (int)(p >> 8);
    }
    __syncthreads();

    if (t < 256) {
        for (int i = excl + v; i < excl + vp; ++i) csr[start + i] = ZROW;
    }
}

// ---------------------------------------------------------------------------
// Gather-mean over bf16 x (proven; at L2/L3-path floor ~78us).
__global__ __launch_bounds__(256, 8) void gather_mean_kernel(const ushort_t* __restrict__ xh,
                                                             ushort_t* __restrict__ mean_bf,
                                                             const int* __restrict__ offsets,
                                                             const int* __restrict__ deg,
                                                             const int* __restrict__ csr) {
    int slot = threadIdx.x >> 6;
    int lane = threadIdx.x & 63;
    int q    = lane >> 4;              // edge-in-quad 0..3
    int fp   = lane & 15;              // feature-quad 0..15
    int node = blockIdx.x * 4 + slot;  // N_NODES % 4 == 0

    int base = offsets[node];
    int cnt  = deg[node];
    int cnt4 = (cnt + 3) & ~3;
    const uint2* xr = (const uint2*)xh;        // rows of 16 uint2 (64 bf16)

    float a0 = 0.f, a1 = 0.f, a2 = 0.f, a3 = 0.f;

    for (int c = 0; c < cnt4; c += 64) {
        int rem = cnt4 - c;                    // multiple of 4
        int sid = (lane < rem) ? csr[base + c + lane] : ZROW;
        int nq = min(64, rem) >> 2;
#define PROC(JJ) { int s = __shfl(sid, 4 * (JJ) + q, 64);                 \
        uint2 u = xr[s * 16 + fp];                                        \
        a0 += bfLO(u.x); a1 += bfHI(u.x); a2 += bfLO(u.y); a3 += bfHI(u.y); }
        int j = 0;
        for (; j + 2 <= nq; j += 2) { PROC(j) PROC(j + 1) }
        for (; j < nq; ++j) { PROC(j) }
#undef PROC
    }

    a0 += __shfl_xor(a0, 16, 64); a1 += __shfl_xor(a1, 16, 64);
    a2 += __shfl_xor(a2, 16, 64); a3 += __shfl_xor(a3, 16, 64);
    a0 += __shfl_xor(a0, 32, 64); a1 += __shfl_xor(a1, 32, 64);
    a2 += __shfl_xor(a2, 32, 64); a3 += __shfl_xor(a3, 32, 64);

    if (lane < 16) {
        float rc = 1.0f / fmaxf((float)cnt, 1.0f);
        uint2 p;
        p.x = pk2bf(a0 * rc, a1 * rc);
        p.y = pk2bf(a2 * rc, a3 * rc);
        *(uint2*)&mean_bf[node * H + fp * 4] = p;
    }
}

// ---------------------------------------------------------------------------
// Transform: xh = bf16(relu(mean @ Wl + bl + x @ Wr)), IN PLACE on xh.
// Weights staged as BF16 planes in LDS (round 15 used f32: 10 b128/kp ->
// now 6 b128/kp; unpack moves to VALU which has headroom). LDS 48 KB.
__global__ __launch_bounds__(256) void transform_kernel(ushort_t* __restrict__ xh,
                                                        const ushort_t* __restrict__ mean_bf,
                                                        const float* __restrict__ Wl,
                                                        const float* __restrict__ bl,
                                                        const float* __restrict__ Wr) {
    __shared__ unsigned sWlh[H * H / 2];   // [k][h] bf16x2, 8 KB
    __shared__ unsigned sWrh[H * H / 2];   // [k][h] bf16x2, 8 KB
    __shared__ unsigned sMT[H / 2][128];   // [kpair][node] bf16x2, 16 KB
    __shared__ unsigned sXT[H / 2][128];   // [kpair][node] bf16x2, 16 KB

    int t = threadIdx.x;
    int node0 = blockIdx.x * 128;

    for (int i = t; i < H * H / 4; i += 256) {     // 1024 float4s per matrix
        float4 a = ((const float4*)Wl)[i];
        float4 b = ((const float4*)Wr)[i];
        ((uint2*)sWlh)[i] = make_uint2(pk2bf(a.x, a.y), pk2bf(a.z, a.w));
        ((uint2*)sWrh)[i] = make_uint2(pk2bf(b.x, b.y), pk2bf(b.z, b.w));
    }
#pragma unroll
    for (int it = 0; it < 8; ++it) {
        int idx = it * 256 + t;
        int n = idx & 127;
        int qd = idx >> 7;                 // uint2-quad 0..15 (k = 4qd..4qd+3)
        int node = node0 + n;
        uint2 mu = make_uint2(0u, 0u);
        uint2 xu = make_uint2(0u, 0u);
        if (node < N_NODES) {
            mu = *(const uint2*)&mean_bf[node * H + qd * 4];
            xu = *(const uint2*)&xh[node * H + qd * 4];
        }
        sMT[qd * 2][n]     = mu.x;
        sMT[qd * 2 + 1][n] = mu.y;
        sXT[qd * 2][n]     = xu.x;
        sXT[qd * 2 + 1][n] = xu.y;
    }
    __syncthreads();

    int tx = t & 7;                        // feature octet: tx*8 .. tx*8+7
    int ty = t >> 3;                       // node quad 0..31
    int nbase = node0 + ty * 4;

    f32x2 acc[4][4];                       // [node][feature-pair]
#pragma unroll
    for (int j = 0; j < 4; ++j)
#pragma unroll
        for (int p = 0; p < 4; ++p) acc[j][p] = (f32x2)(0.0f);

    for (int kp = 0; kp < H / 2; ++kp) {   // k-pairs
        uint4 mu = *(const uint4*)&sMT[kp][ty * 4];   // 4 nodes x {k0,k1}
        uint4 xu = *(const uint4*)&sXT[kp][ty * 4];
        int k0 = kp * 2;
        uint4 wl0u = *(const uint4*)&sWlh[k0 * (H / 2) + tx * 4];        // k0, 8 feats
        uint4 wl1u = *(const uint4*)&sWlh[(k0 + 1) * (H / 2) + tx * 4];  // k1
        uint4 wr0u = *(const uint4*)&sWrh[k0 * (H / 2) + tx * 4];
        uint4 wr1u = *(const uint4*)&sWrh[(k0 + 1) * (H / 2) + tx * 4];
        const unsigned wl0a[4] = {wl0u.x, wl0u.y, wl0u.z, wl0u.w};
        const unsigned wl1a[4] = {wl1u.x, wl1u.y, wl1u.z, wl1u.w};
        const unsigned wr0a[4] = {wr0u.x, wr0u.y, wr0u.z, wr0u.w};
        const unsigned wr1a[4] = {wr1u.x, wr1u.y, wr1u.z, wr1u.w};
        f32x2 wl0p[4], wl1p[4], wr0p[4], wr1p[4];
#pragma unroll
        for (int p = 0; p < 4; ++p) {
            wl0p[p] = (f32x2){bfLO(wl0a[p]), bfHI(wl0a[p])};
            wl1p[p] = (f32x2){bfLO(wl1a[p]), bfHI(wl1a[p])};
            wr0p[p] = (f32x2){bfLO(wr0a[p]), bfHI(wr0a[p])};
            wr1p[p] = (f32x2){bfLO(wr1a[p]), bfHI(wr1a[p])};
        }
        const unsigned mua[4] = {mu.x, mu.y, mu.z, mu.w};
        const unsigned xua[4] = {xu.x, xu.y, xu.z, xu.w};
#pragma unroll
        for (int j = 0; j < 4; ++j) {
            f32x2 m0 = (f32x2)(bfLO(mua[j]));
            f32x2 m1 = (f32x2)(bfHI(mua[j]));
            f32x2 x0 = (f32x2)(bfLO(xua[j]));
            f32x2 x1 = (f32x2)(bfHI(xua[j]));
#pragma unroll
            for (int p = 0; p < 4; ++p) {
                f32x2 a = acc[j][p];
                a = __builtin_elementwise_fma(m0, wl0p[p], a);
                a = __builtin_elementwise_fma(x0, wr0p[p], a);
                a = __builtin_elementwise_fma(m1, wl1p[p], a);
                a = __builtin_elementwise_fma(x1, wr1p[p], a);
                acc[j][p] = a;
            }
        }
    }

    float4 b0 = *(const float4*)&bl[tx * 8];
    float4 b1 = *(const float4*)&bl[tx * 8 + 4];
    f32x2 bias[4] = {{b0.x, b0.y}, {b0.z, b0.w}, {b1.x, b1.y}, {b1.z, b1.w}};
#pragma unroll
    for (int j = 0; j < 4; ++j) {
        int node = nbase + j;
        if (node < N_NODES) {
            uint4 pk;
            unsigned w[4];
#pragma unroll
            for (int p = 0; p < 4; ++p) {
                float o0 = fmaxf(acc[j][p].x + bias[p].x, 0.0f);
                float o1 = fmaxf(acc[j][p].y + bias[p].y, 0.0f);
                w[p] = pk2bf(o0, o1);
            }
            pk.x = w[0]; pk.y = w[1]; pk.z = w[2]; pk.w = w[3];
            *(uint4*)&xh[node * H + tx * 8] = pk;
        }
    }
}

// ---------------------------------------------------------------------------
// Final MLP, register-tiled like the transform: 128 items/block, 256 threads,
// thread = 2 items x 8 hidden. W1 staged as bf16 plane; pair-features staged
// transposed bf16-packed. Replaces the per-thread 256x ds_read_b32 version.
__global__ __launch_bounds__(256) void mlp_kernel(const ushort_t* __restrict__ xh,
                                                  const int* __restrict__ uids,
                                                  const int* __restrict__ iids,
                                                  const float* __restrict__ W1,
                                                  const float* __restrict__ b1,
                                                  const float* __restrict__ W2,
                                                  const float* __restrict__ b2,
                                                  float* __restrict__ out) {
    __shared__ unsigned sW1h[2 * H * MLP_HIDDEN / 2];  // [k][h] bf16x2, 8 KB
    __shared__ unsigned sPT[H][128];                   // [kpair][item] bf16x2, 32 KB
    __shared__ float    sW2f[MLP_HIDDEN];
    __shared__ float    sB1f[MLP_HIDDEN];
    __shared__ int      sUid[128];
    __shared__ int      sIid[128];

    int t = threadIdx.x;
    int item0 = blockIdx.x * 128;

    // stage W1 (128x32 f32 -> bf16 pairs), biases, ids
    for (int i = t; i < 2 * H * MLP_HIDDEN / 4; i += 256) {   // 1024 float4s
        float4 a = ((const float4*)W1)[i];
        ((uint2*)sW1h)[i] = make_uint2(pk2bf(a.x, a.y), pk2bf(a.z, a.w));
    }
    if (t < MLP_HIDDEN) {
        sW2f[t] = W2[t];
        sB1f[t] = b1[t];
    }
    if (t < 128) {
        int g = item0 + t;
        sUid[t] = (g < BATCH) ? uids[g] : 0;
        sIid[t] = (g < BATCH) ? iids[g] : 0;
    }
    __syncthreads();

    // stage pair features transposed: chunk = half*16 + fq; 32 chunks x 128 items
    const uint2* xr = (const uint2*)xh;
#pragma unroll
    for (int it = 0; it < 16; ++it) {
        int idx = it * 256 + t;
        int item = idx & 127;
        int chunk = idx >> 7;              // 0..31
        int half = chunk >> 4;             // 0: user, 1: item
        int fq = chunk & 15;               // uint2-quad within row
        int row = half ? (sIid[item] + NUM_USERS) : sUid[item];
        uint2 v = xr[row * 16 + fq];
        int kp0 = half * 32 + fq * 2;
        sPT[kp0][item]     = v.x;
        sPT[kp0 + 1][item] = v.y;
    }
    __syncthreads();

    int tx = t & 3;                        // hidden octet: tx*8 .. tx*8+7
    int ty = t >> 2;                       // item pair 0..63
    int ibase = item0 + ty * 2;

    f32x2 acc[2][4];                       // [item][hidden-pair]
#pragma unroll
    for (int j = 0; j < 2; ++j)
#pragma unroll
        for (int p = 0; p < 4; ++p) acc[j][p] = (f32x2)(0.0f);

    for (int kp = 0; kp < H; ++kp) {       // 64 k-pairs (2H = 128 k)
        uint2 pv = *(const uint2*)&sPT[kp][ty * 2];    // 2 items x {k0,k1}
        int k0 = kp * 2;
        uint4 w0u = *(const uint4*)&sW1h[k0 * (MLP_HIDDEN / 2) + tx * 4];
        uint4 w1u = *(const uint4*)&sW1h[(k0 + 1) * (MLP_HIDDEN / 2) + tx * 4];
        const unsigned w0a[4] = {w0u.x, w0u.y, w0u.z, w0u.w};
        const unsigned w1a[4] = {w1u.x, w1u.y, w1u.z, w1u.w};
        f32x2 w0p[4], w1p[4];
#pragma unroll
        for (int p = 0; p < 4; ++p) {
            w0p[p] = (f32x2){bfLO(w0a[p]), bfHI(w0a[p])};
            w1p[p] = (f32x2){bfLO(w1a[p]), bfHI(w1a[p])};
        }
        const unsigned pva[2] = {pv.x, pv.y};
#pragma unroll
        for (int j = 0; j < 2; ++j) {
            f32x2 m0 = (f32x2)(bfLO(pva[j]));
            f32x2 m1 = (f32x2)(bfHI(pva[j]));
#pragma unroll
            for (int p = 0; p < 4; ++p) {
                f32x2 a = acc[j][p];
                a = __builtin_elementwise_fma(m0, w0p[p], a);
                a = __builtin_elementwise_fma(m1, w1p[p], a);
                acc[j][p] = a;
            }
        }
    }

    // epilogue: bias + relu + dot W2-octet, then reduce across the 4 tx lanes
    float b2v = b2[0];
#pragma unroll
    for (int j = 0; j < 2; ++j) {
        float partial = 0.0f;
#pragma unroll
        for (int p = 0; p < 4; ++p) {
            float h0 = fmaxf(acc[j][p].x + sB1f[tx * 8 + p * 2],     0.0f);
            float h1 = fmaxf(acc[j][p].y + sB1f[tx * 8 + p * 2 + 1], 0.0f);
            partial = fmaf(h0, sW2f[tx * 8 + p * 2],     partial);
            partial = fmaf(h1, sW2f[tx * 8 + p * 2 + 1], partial);
        }
        partial += __shfl_xor(partial, 1, 64);
        partial += __shfl_xor(partial, 2, 64);
        int g = ibase + j;
        if (tx == 0 && g < BATCH)
            out[g] = fminf(fmaxf(partial + b2v, 1.0f), 5.0f);
    }
}

// ---------------------------------------------------------------------------
extern "C" void kernel_launch(void* const* d_in, const int* in_sizes, int n_in,
                              void* d_out, int out_size, void* d_ws, size_t ws_size,
                              hipStream_t stream) {
    const int*   edge_index = (const int*)d_in[0];
    const int*   user_ids   = (const int*)d_in[1];
    const int*   item_ids   = (const int*)d_in[2];
    const float* user_emb   = (const float*)d_in[3];
    const float* item_emb   = (const float*)d_in[4];
    const float* Wl         = (const float*)d_in[5];
    const float* bl         = (const float*)d_in[6];
    const float* Wr         = (const float*)d_in[7];
    const float* W1         = (const float*)d_in[8];
    const float* b1         = (const float*)d_in[9];
    const float* W2         = (const float*)d_in[10];
    const float* b2         = (const float*)d_in[11];
    float* out = (float*)d_out;

    const int* src = edge_index;
    const int* dst = edge_index + N_EDGES;

    const size_t NH = (size_t)N_NODES * H;
    ushort_t* xh      = (ushort_t*)d_ws;                 // (N_NODES+1) bf16 rows
    int* ebuf         = (int*)(xh + NH + H);             // 19.2 MB
    ushort_t* mean_bf = (ushort_t*)ebuf;                 // bf16 overlay (fits)
    int* deg          = ebuf + (size_t)NBUCK * BCAP;     // 600 KB
    int* offsets      = deg + N_NODES;                   // 600 KB
    int* bucketCnt    = offsets + N_NODES;               // 2.3 KB
    int* csr          = bucketCnt + NBUCK;               // 19.2 MB (BCAP-strided)

    init_kernel<<<(N_NODES * H / 4) / 256, 256, 0, stream>>>(user_emb, item_emb, xh);
    hipMemsetAsync(xh + NH, 0, H * sizeof(ushort_t), stream);   // zero row (ZROW)

    // CSR build: fixed-capacity counting sort (graph identical across layers)
    hipMemsetAsync(bucketCnt, 0, NBUCK * sizeof(int), stream);
    bucket_scatter_kernel<<<(N_EDGES + SCHUNK - 1) / SCHUNK, 256, 0, stream>>>(
        src, dst, bucketCnt, ebuf);
    bucket_build_kernel<<<NBUCK, 1024, 0, stream>>>(ebuf, bucketCnt, deg, offsets, csr);

    const int TGRID = (N_NODES + 127) / 128;             // 1172
    for (int l = 0; l < 3; ++l) {
        gather_mean_kernel<<<N_NODES / 4, 256, 0, stream>>>(xh, mean_bf, offsets, deg, csr);
        transform_kernel<<<TGRID, 256, 0, stream>>>(
            xh, mean_bf, Wl + (size_t)l * H * H, bl + (size_t)l * H,
            Wr + (size_t)l * H * H);
    }

    mlp_kernel<<<(BATCH + 127) / 128, 256, 0, stream>>>(xh, user_ids, item_ids,
                                                        W1, b1, W2, b2, out);
}

// Round 18
// 476.037 us; speedup vs baseline: 1.1787x; 1.0242x over previous
//
#include <hip/hip_runtime.h>
#include <hip/hip_bf16.h>
#include <hip/hip_fp8.h>

#define NUM_USERS 100000
#define NUM_ITEMS 50000
#define N_NODES   150000
#define N_EDGES   4000000
#define H         64
#define BATCH     100000
#define MLP_HIDDEN 32
#define NBUCK     586          // ceil(N_NODES / 256); bucket = dst >> 8
#define BCAP      8192         // fixed bucket capacity (padded total <= ~7900)
#define ZROW      N_NODES      // index of the all-zero row appended to xh/xq

typedef unsigned short ushort_t;
typedef float f32x2 __attribute__((ext_vector_type(2)));

__device__ __forceinline__ ushort_t f2bf(float f) {   // round-to-nearest-even
    unsigned u = __float_as_uint(f);
    u = u + 0x7FFFu + ((u >> 16) & 1u);
    return (ushort_t)(u >> 16);
}
__device__ __forceinline__ unsigned pk2bf(float a, float b) {
    return (unsigned)f2bf(a) | ((unsigned)f2bf(b) << 16);
}
__device__ __forceinline__ float bfLO(unsigned u) { return __uint_as_float(u << 16); }
__device__ __forceinline__ float bfHI(unsigned u) { return __uint_as_float(u & 0xFFFF0000u); }

// ---- fp8 e4m3 pack/unpack (HW converts on gfx950; guarded fallback) -------
// NOTE: the builtin's word-select must be a LITERAL constant (round 17
// compile failure) -> template parameter, folds per-instantiation.
#if __has_builtin(__builtin_amdgcn_cvt_pk_f32_fp8) && __has_builtin(__builtin_amdgcn_cvt_pk_fp8_f32)
#define FP8_HW 1
#endif

template <bool HI>
__device__ __forceinline__ f32x2 fp8x2_to_f32(unsigned u) {
#ifdef FP8_HW
    return __builtin_amdgcn_cvt_pk_f32_fp8(u, HI);
#else
    unsigned b0 = HI ? ((u >> 16) & 0xFFu) : (u & 0xFFu);
    unsigned b1 = HI ? ((u >> 24) & 0xFFu) : ((u >> 8) & 0xFFu);
    f32x2 r;
    {
        unsigned em = b0 & 0x7Fu;
        float mag = (em >= 8u) ? __uint_as_float((em << 20) + 0x3C000000u)
                               : (float)em * 0.001953125f;
        r.x = (b0 & 0x80u) ? -mag : mag;
    }
    {
        unsigned em = b1 & 0x7Fu;
        float mag = (em >= 8u) ? __uint_as_float((em << 20) + 0x3C000000u)
                               : (float)em * 0.001953125f;
        r.y = (b1 & 0x80u) ? -mag : mag;
    }
    return r;
#endif
}

__device__ __forceinline__ unsigned f32x4_to_fp8(float a, float b, float c, float d) {
#ifdef FP8_HW
    unsigned r = (unsigned)__builtin_amdgcn_cvt_pk_fp8_f32(a, b, 0, false);
    r = (unsigned)__builtin_amdgcn_cvt_pk_fp8_f32(c, d, (int)r, true);
    return r;
#else
    __hip_fp8_e4m3 qa(a), qb(b), qc(c), qd(d);
    return (unsigned)qa.__x | ((unsigned)qb.__x << 8) |
           ((unsigned)qc.__x << 16) | ((unsigned)qd.__x << 24);
#endif
}

// ---------------------------------------------------------------------------
// Init: xh = bf16(concat(ue, ie)), xq = fp8(concat(ue, ie)).
__global__ __launch_bounds__(256) void init_kernel(const float* __restrict__ ue,
                                                   const float* __restrict__ ie,
                                                   ushort_t* __restrict__ xh,
                                                   unsigned* __restrict__ xq) {
    int i = blockIdx.x * 256 + threadIdx.x;        // float4 index, exact grid
    const int UN4 = NUM_USERS * H / 4;
    float4 v = (i < UN4) ? ((const float4*)ue)[i] : ((const float4*)ie)[i - UN4];
    uint2 p;
    p.x = pk2bf(v.x, v.y);
    p.y = pk2bf(v.z, v.w);
    ((uint2*)xh)[i] = p;
    xq[i] = f32x4_to_fp8(v.x, v.y, v.z, v.w);
}

// ---------------------------------------------------------------------------
// CSR build pass 1: LDS-SORTED scatter into fixed-capacity buckets (proven).
// Entry packed as (src << 8) | (dst & 255).
#define SCHUNK 4096
#define SPT    (SCHUNK / 256)          // 16 edges per thread
__global__ __launch_bounds__(256) void bucket_scatter_kernel(const int* __restrict__ src,
                                                             const int* __restrict__ dst,
                                                             int* __restrict__ bucketCnt,
                                                             int* __restrict__ ebuf) {
    __shared__ int      histL[NBUCK];
    __shared__ int      startL[NBUCK];
    __shared__ int      adjL[NBUCK];
    __shared__ int      curL[NBUCK];
    __shared__ unsigned staged[SCHUNK];
    __shared__ ushort_t sbuck[SCHUNK];

    int t = threadIdx.x;
    int base = blockIdx.x * SCHUNK;
    int nst = min(SCHUNK, N_EDGES - base);

    for (int i = t; i < NBUCK; i += 256) histL[i] = 0;
    __syncthreads();

    int myd[SPT], mys[SPT];
#pragma unroll
    for (int k = 0; k < SPT; ++k) {
        int e = base + k * 256 + t;
        int d = (e < N_EDGES) ? dst[e] : -1;
        mys[k] = (e < N_EDGES) ? src[e] : 0;
        myd[k] = d;
        if (d >= 0) atomicAdd(&histL[d >> 8], 1);
    }
    __syncthreads();

    if (t < 64) {
        const int CH = (NBUCK + 63) / 64;
        int s0 = t * CH;
        int s1 = min(s0 + CH, NBUCK);
        int s = 0;
        for (int i = s0; i < s1; ++i) s += histL[i];
        int v = s;
#pragma unroll
        for (int off = 1; off < 64; off <<= 1) {
            int u = __shfl_up(v, off, 64);
            if (t >= off) v += u;
        }
        int run = v - s;
        for (int i = s0; i < s1; ++i) {
            startL[i] = run;
            run += histL[i];
        }
    }
    __syncthreads();

    for (int b = t; b < NBUCK; b += 256) {
        int h = histL[b];
        int res = h ? (b * BCAP + atomicAdd(&bucketCnt[b], h)) : 0;
        adjL[b] = res - startL[b];
        curL[b] = startL[b];
    }
    __syncthreads();

#pragma unroll
    for (int k = 0; k < SPT; ++k) {
        int d = myd[k];
        if (d >= 0) {
            int b = d >> 8;
            int pos = atomicAdd(&curL[b], 1);
            staged[pos] = ((unsigned)mys[k] << 8) | (unsigned)(d & 255);
            sbuck[pos] = (ushort_t)b;
        }
    }
    __syncthreads();

    for (int i = t; i < nst; i += 256) {
        int b = sbuck[i];
        ebuf[adjL[b] + i] = (int)staged[i];
    }
}

// CSR build pass 2: one block per bucket; segments padded to multiple of 4
// with ZROW so the gather needs no per-quad tail masking.
__global__ __launch_bounds__(1024) void bucket_build_kernel(const int* __restrict__ ebuf,
                                                            const int* __restrict__ bucketCnt,
                                                            int* __restrict__ deg,
                                                            int* __restrict__ offsets,
                                                            int* __restrict__ csr) {
    __shared__ int degL[256];
    __shared__ int scanL[256];
    __shared__ int curL[256];
    int t = threadIdx.x;
    int b = blockIdx.x;
    int nodeBase = b << 8;
    int start = b * BCAP;
    int cnt = bucketCnt[b];

    if (t < 256) degL[t] = 0;
    __syncthreads();
    for (int i = t; i < cnt; i += 1024)
        atomicAdd(&degL[ebuf[start + i] & 255], 1);
    __syncthreads();

    int v  = (t < 256) ? degL[t] : 0;
    int vp = (v + 3) & ~3;                 // padded degree
    if (t < 256) scanL[t] = vp;
    __syncthreads();
#pragma unroll
    for (int off = 1; off < 256; off <<= 1) {
        int u = (t >= off && t < 256) ? scanL[t - off] : 0;
        __syncthreads();
        if (t < 256) scanL[t] += u;
        __syncthreads();
    }

    int excl = 0;
    if (t < 256) {
        excl = scanL[t] - vp;
        int node = nodeBase + t;
        if (node < N_NODES) {
            deg[node] = v;
            offsets[node] = start + excl;
        }
        curL[t] = excl;
    }
    __syncthreads();

    for (int i = t; i < cnt; i += 1024) {
        unsigned p = (unsigned)ebuf[start + i];
        int pos = atomicAdd(&curL[p & 255u], 1);
        csr[start + pos] = (int)(p >> 8);
    }
    __syncthreads();

    if (t < 256) {
        for (int i = excl + v; i < excl + vp; ++i) csr[start + i] = ZROW;
    }
}

// ---------------------------------------------------------------------------
// Gather-mean over FP8 x: one wave per node, 4 edges per wave-instruction.
// Lane = (edge-in-quad q, feature-quad fp); each lane loads ONE uint = 4 fp8
// features; HW cvt_pk_f32_fp8 unpacks 2/instr. Mean written bf16. Table is
// 9.6 MB (was 19.2 bf16) -> per-XCD L2 replication + capacity traffic halves.
__global__ __launch_bounds__(256, 8) void gather_mean_kernel(const unsigned* __restrict__ xq,
                                                             ushort_t* __restrict__ mean_bf,
                                                             const int* __restrict__ offsets,
                                                             const int* __restrict__ deg,
                                                             const int* __restrict__ csr) {
    int slot = threadIdx.x >> 6;
    int lane = threadIdx.x & 63;
    int q    = lane >> 4;              // edge-in-quad 0..3
    int fp   = lane & 15;              // feature-quad 0..15 (4 fp8 each)
    int node = blockIdx.x * 4 + slot;  // N_NODES % 4 == 0

    int base = offsets[node];
    int cnt  = deg[node];
    int cnt4 = (cnt + 3) & ~3;

    float a0 = 0.f, a1 = 0.f, a2 = 0.f, a3 = 0.f;

    for (int c = 0; c < cnt4; c += 64) {
        int rem = cnt4 - c;                    // multiple of 4
        int sid = (lane < rem) ? csr[base + c + lane] : ZROW;
        int nq = min(64, rem) >> 2;
#define PROC(JJ) { int s = __shfl(sid, 4 * (JJ) + q, 64);                 \
        unsigned u = xq[s * 16 + fp];                                     \
        f32x2 lo = fp8x2_to_f32<false>(u);                                \
        f32x2 hi = fp8x2_to_f32<true>(u);                                 \
        a0 += lo.x; a1 += lo.y; a2 += hi.x; a3 += hi.y; }
        int j = 0;
        for (; j + 2 <= nq; j += 2) { PROC(j) PROC(j + 1) }
        for (; j < nq; ++j) { PROC(j) }
#undef PROC
    }

    a0 += __shfl_xor(a0, 16, 64); a1 += __shfl_xor(a1, 16, 64);
    a2 += __shfl_xor(a2, 16, 64); a3 += __shfl_xor(a3, 16, 64);
    a0 += __shfl_xor(a0, 32, 64); a1 += __shfl_xor(a1, 32, 64);
    a2 += __shfl_xor(a2, 32, 64); a3 += __shfl_xor(a3, 32, 64);

    if (lane < 16) {
        float rc = 1.0f / fmaxf((float)cnt, 1.0f);
        uint2 p;
        p.x = pk2bf(a0 * rc, a1 * rc);
        p.y = pk2bf(a2 * rc, a3 * rc);
        *(uint2*)&mean_bf[node * H + fp * 4] = p;
    }
}

// ---------------------------------------------------------------------------
// Transform: relu(mean @ Wl + bl + x @ Wr) -> xh (bf16, in place) and xq
// (fp8, for the next gather). Weights staged as BF16 planes in LDS.
__global__ __launch_bounds__(256) void transform_kernel(ushort_t* __restrict__ xh,
                                                        unsigned* __restrict__ xq,
                                                        const ushort_t* __restrict__ mean_bf,
                                                        const float* __restrict__ Wl,
                                                        const float* __restrict__ bl,
                                                        const float* __restrict__ Wr,
                                                        int writeQ) {
    __shared__ unsigned sWlh[H * H / 2];   // [k][h] bf16x2, 8 KB
    __shared__ unsigned sWrh[H * H / 2];   // [k][h] bf16x2, 8 KB
    __shared__ unsigned sMT[H / 2][128];   // [kpair][node] bf16x2, 16 KB
    __shared__ unsigned sXT[H / 2][128];   // [kpair][node] bf16x2, 16 KB

    int t = threadIdx.x;
    int node0 = blockIdx.x * 128;

    for (int i = t; i < H * H / 4; i += 256) {     // 1024 float4s per matrix
        float4 a = ((const float4*)Wl)[i];
        float4 b = ((const float4*)Wr)[i];
        ((uint2*)sWlh)[i] = make_uint2(pk2bf(a.x, a.y), pk2bf(a.z, a.w));
        ((uint2*)sWrh)[i] = make_uint2(pk2bf(b.x, b.y), pk2bf(b.z, b.w));
    }
#pragma unroll
    for (int it = 0; it < 8; ++it) {
        int idx = it * 256 + t;
        int n = idx & 127;
        int qd = idx >> 7;                 // uint2-quad 0..15 (k = 4qd..4qd+3)
        int node = node0 + n;
        uint2 mu = make_uint2(0u, 0u);
        uint2 xu = make_uint2(0u, 0u);
        if (node < N_NODES) {
            mu = *(const uint2*)&mean_bf[node * H + qd * 4];
            xu = *(const uint2*)&xh[node * H + qd * 4];
        }
        sMT[qd * 2][n]     = mu.x;
        sMT[qd * 2 + 1][n] = mu.y;
        sXT[qd * 2][n]     = xu.x;
        sXT[qd * 2 + 1][n] = xu.y;
    }
    __syncthreads();

    int tx = t & 7;                        // feature octet: tx*8 .. tx*8+7
    int ty = t >> 3;                       // node quad 0..31
    int nbase = node0 + ty * 4;

    f32x2 acc[4][4];                       // [node][feature-pair]
#pragma unroll
    for (int j = 0; j < 4; ++j)
#pragma unroll
        for (int p = 0; p < 4; ++p) acc[j][p] = (f32x2)(0.0f);

    for (int kp = 0; kp < H / 2; ++kp) {   // k-pairs
        uint4 mu = *(const uint4*)&sMT[kp][ty * 4];   // 4 nodes x {k0,k1}
        uint4 xu = *(const uint4*)&sXT[kp][ty * 4];
        int k0 = kp * 2;
        uint4 wl0u = *(const uint4*)&sWlh[k0 * (H / 2) + tx * 4];
        uint4 wl1u = *(const uint4*)&sWlh[(k0 + 1) * (H / 2) + tx * 4];
        uint4 wr0u = *(const uint4*)&sWrh[k0 * (H / 2) + tx * 4];
        uint4 wr1u = *(const uint4*)&sWrh[(k0 + 1) * (H / 2) + tx * 4];
        const unsigned wl0a[4] = {wl0u.x, wl0u.y, wl0u.z, wl0u.w};
        const unsigned wl1a[4] = {wl1u.x, wl1u.y, wl1u.z, wl1u.w};
        const unsigned wr0a[4] = {wr0u.x, wr0u.y, wr0u.z, wr0u.w};
        const unsigned wr1a[4] = {wr1u.x, wr1u.y, wr1u.z, wr1u.w};
        f32x2 wl0p[4], wl1p[4], wr0p[4], wr1p[4];
#pragma unroll
        for (int p = 0; p < 4; ++p) {
            wl0p[p] = (f32x2){bfLO(wl0a[p]), bfHI(wl0a[p])};
            wl1p[p] = (f32x2){bfLO(wl1a[p]), bfHI(wl1a[p])};
            wr0p[p] = (f32x2){bfLO(wr0a[p]), bfHI(wr0a[p])};
            wr1p[p] = (f32x2){bfLO(wr1a[p]), bfHI(wr1a[p])};
        }
        const unsigned mua[4] = {mu.x, mu.y, mu.z, mu.w};
        const unsigned xua[4] = {xu.x, xu.y, xu.z, xu.w};
#pragma unroll
        for (int j = 0; j < 4; ++j) {
            f32x2 m0 = (f32x2)(bfLO(mua[j]));
            f32x2 m1 = (f32x2)(bfHI(mua[j]));
            f32x2 x0 = (f32x2)(bfLO(xua[j]));
            f32x2 x1 = (f32x2)(bfHI(xua[j]));
#pragma unroll
            for (int p = 0; p < 4; ++p) {
                f32x2 a = acc[j][p];
                a = __builtin_elementwise_fma(m0, wl0p[p], a);
                a = __builtin_elementwise_fma(x0, wr0p[p], a);
                a = __builtin_elementwise_fma(m1, wl1p[p], a);
                a = __builtin_elementwise_fma(x1, wr1p[p], a);
                acc[j][p] = a;
            }
        }
    }

    float4 b0 = *(const float4*)&bl[tx * 8];
    float4 b1 = *(const float4*)&bl[tx * 8 + 4];
    f32x2 bias[4] = {{b0.x, b0.y}, {b0.z, b0.w}, {b1.x, b1.y}, {b1.z, b1.w}};
#pragma unroll
    for (int j = 0; j < 4; ++j) {
        int node = nbase + j;
        if (node < N_NODES) {
            float o[8];
#pragma unroll
            for (int p = 0; p < 4; ++p) {
                o[p * 2]     = fmaxf(acc[j][p].x + bias[p].x, 0.0f);
                o[p * 2 + 1] = fmaxf(acc[j][p].y + bias[p].y, 0.0f);
            }
            uint4 pk;
            pk.x = pk2bf(o[0], o[1]);
            pk.y = pk2bf(o[2], o[3]);
            pk.z = pk2bf(o[4], o[5]);
            pk.w = pk2bf(o[6], o[7]);
            *(uint4*)&xh[node * H + tx * 8] = pk;
            if (writeQ) {
                uint2 qk;
                qk.x = f32x4_to_fp8(o[0], o[1], o[2], o[3]);
                qk.y = f32x4_to_fp8(o[4], o[5], o[6], o[7]);
                *(uint2*)&xq[node * 16 + tx * 2] = qk;
            }
        }
    }
}

// ---------------------------------------------------------------------------
// Final MLP, register-tiled: 128 items/block, thread = 2 items x 8 hidden.
__global__ __launch_bounds__(256) void mlp_kernel(const ushort_t* __restrict__ xh,
                                                  const int* __restrict__ uids,
                                                  const int* __restrict__ iids,
                                                  const float* __restrict__ W1,
                                                  const float* __restrict__ b1,
                                                  const float* __restrict__ W2,
                                                  const float* __restrict__ b2,
                                                  float* __restrict__ out) {
    __shared__ unsigned sW1h[2 * H * MLP_HIDDEN / 2];  // [k][h] bf16x2, 8 KB
    __shared__ unsigned sPT[H][128];                   // [kpair][item] bf16x2, 32 KB
    __shared__ float    sW2f[MLP_HIDDEN];
    __shared__ float    sB1f[MLP_HIDDEN];
    __shared__ int      sUid[128];
    __shared__ int      sIid[128];

    int t = threadIdx.x;
    int item0 = blockIdx.x * 128;

    for (int i = t; i < 2 * H * MLP_HIDDEN / 4; i += 256) {   // 1024 float4s
        float4 a = ((const float4*)W1)[i];
        ((uint2*)sW1h)[i] = make_uint2(pk2bf(a.x, a.y), pk2bf(a.z, a.w));
    }
    if (t < MLP_HIDDEN) {
        sW2f[t] = W2[t];
        sB1f[t] = b1[t];
    }
    if (t < 128) {
        int g = item0 + t;
        sUid[t] = (g < BATCH) ? uids[g] : 0;
        sIid[t] = (g < BATCH) ? iids[g] : 0;
    }
    __syncthreads();

    const uint2* xr = (const uint2*)xh;
#pragma unroll
    for (int it = 0; it < 16; ++it) {
        int idx = it * 256 + t;
        int item = idx & 127;
        int chunk = idx >> 7;              // 0..31
        int half = chunk >> 4;             // 0: user, 1: item
        int fq = chunk & 15;               // uint2-quad within row
        int row = half ? (sIid[item] + NUM_USERS) : sUid[item];
        uint2 v = xr[row * 16 + fq];
        int kp0 = half * 32 + fq * 2;
        sPT[kp0][item]     = v.x;
        sPT[kp0 + 1][item] = v.y;
    }
    __syncthreads();

    int tx = t & 3;                        // hidden octet: tx*8 .. tx*8+7
    int ty = t >> 2;                       // item pair 0..63
    int ibase = item0 + ty * 2;

    f32x2 acc[2][4];                       // [item][hidden-pair]
#pragma unroll
    for (int j = 0; j < 2; ++j)
#pragma unroll
        for (int p = 0; p < 4; ++p) acc[j][p] = (f32x2)(0.0f);

    for (int kp = 0; kp < H; ++kp) {       // 64 k-pairs (2H = 128 k)
        uint2 pv = *(const uint2*)&sPT[kp][ty * 2];    // 2 items x {k0,k1}
        int k0 = kp * 2;
        uint4 w0u = *(const uint4*)&sW1h[k0 * (MLP_HIDDEN / 2) + tx * 4];
        uint4 w1u = *(const uint4*)&sW1h[(k0 + 1) * (MLP_HIDDEN / 2) + tx * 4];
        const unsigned w0a[4] = {w0u.x, w0u.y, w0u.z, w0u.w};
        const unsigned w1a[4] = {w1u.x, w1u.y, w1u.z, w1u.w};
        f32x2 w0p[4], w1p[4];
#pragma unroll
        for (int p = 0; p < 4; ++p) {
            w0p[p] = (f32x2){bfLO(w0a[p]), bfHI(w0a[p])};
            w1p[p] = (f32x2){bfLO(w1a[p]), bfHI(w1a[p])};
        }
        const unsigned pva[2] = {pv.x, pv.y};
#pragma unroll
        for (int j = 0; j < 2; ++j) {
            f32x2 m0 = (f32x2)(bfLO(pva[j]));
            f32x2 m1 = (f32x2)(bfHI(pva[j]));
#pragma unroll
            for (int p = 0; p < 4; ++p) {
                f32x2 a = acc[j][p];
                a = __builtin_elementwise_fma(m0, w0p[p], a);
                a = __builtin_elementwise_fma(m1, w1p[p], a);
                acc[j][p] = a;
            }
        }
    }

    float b2v = b2[0];
#pragma unroll
    for (int j = 0; j < 2; ++j) {
        float partial = 0.0f;
#pragma unroll
        for (int p = 0; p < 4; ++p) {
            float h0 = fmaxf(acc[j][p].x + sB1f[tx * 8 + p * 2],     0.0f);
            float h1 = fmaxf(acc[j][p].y + sB1f[tx * 8 + p * 2 + 1], 0.0f);
            partial = fmaf(h0, sW2f[tx * 8 + p * 2],     partial);
            partial = fmaf(h1, sW2f[tx * 8 + p * 2 + 1], partial);
        }
        partial += __shfl_xor(partial, 1, 64);
        partial += __shfl_xor(partial, 2, 64);
        int g = ibase + j;
        if (tx == 0 && g < BATCH)
            out[g] = fminf(fmaxf(partial + b2v, 1.0f), 5.0f);
    }
}

// ---------------------------------------------------------------------------
extern "C" void kernel_launch(void* const* d_in, const int* in_sizes, int n_in,
                              void* d_out, int out_size, void* d_ws, size_t ws_size,
                              hipStream_t stream) {
    const int*   edge_index = (const int*)d_in[0];
    const int*   user_ids   = (const int*)d_in[1];
    const int*   item_ids   = (const int*)d_in[2];
    const float* user_emb   = (const float*)d_in[3];
    const float* item_emb   = (const float*)d_in[4];
    const float* Wl         = (const float*)d_in[5];
    const float* bl         = (const float*)d_in[6];
    const float* Wr         = (const float*)d_in[7];
    const float* W1         = (const float*)d_in[8];
    const float* b1         = (const float*)d_in[9];
    const float* W2         = (const float*)d_in[10];
    const float* b2         = (const float*)d_in[11];
    float* out = (float*)d_out;

    const int* src = edge_index;
    const int* dst = edge_index + N_EDGES;

    const size_t NH = (size_t)N_NODES * H;
    ushort_t* xh      = (ushort_t*)d_ws;                 // (N_NODES+1) bf16 rows, 19.2 MB
    unsigned* xq      = (unsigned*)(xh + NH + H);        // (N_NODES+1) fp8 rows, 9.6 MB
    int* ebuf         = (int*)(xq + (NH + H) / 4);       // 19.2 MB
    ushort_t* mean_bf = (ushort_t*)ebuf;                 // bf16 overlay (CSR build done first)
    int* deg          = ebuf + (size_t)NBUCK * BCAP;     // 600 KB
    int* offsets      = deg + N_NODES;                   // 600 KB
    int* bucketCnt    = offsets + N_NODES;               // 2.3 KB
    int* csr          = bucketCnt + NBUCK;               // 19.2 MB (BCAP-strided)

    init_kernel<<<(N_NODES * H / 4) / 256, 256, 0, stream>>>(user_emb, item_emb, xh, xq);
    hipMemsetAsync(xh + NH, 0, H * sizeof(ushort_t), stream);   // zero bf16 row (ZROW)
    hipMemsetAsync(xq + NH / 4, 0, H, stream);                  // zero fp8 row (ZROW)

    // CSR build: fixed-capacity counting sort (graph identical across layers)
    hipMemsetAsync(bucketCnt, 0, NBUCK * sizeof(int), stream);
    bucket_scatter_kernel<<<(N_EDGES + SCHUNK - 1) / SCHUNK, 256, 0, stream>>>(
        src, dst, bucketCnt, ebuf);
    bucket_build_kernel<<<NBUCK, 1024, 0, stream>>>(ebuf, bucketCnt, deg, offsets, csr);

    const int TGRID = (N_NODES + 127) / 128;             // 1172
    for (int l = 0; l < 3; ++l) {
        gather_mean_kernel<<<N_NODES / 4, 256, 0, stream>>>(xq, mean_bf, offsets, deg, csr);
        transform_kernel<<<TGRID, 256, 0, stream>>>(
            xh, xq, mean_bf, Wl + (size_t)l * H * H, bl + (size_t)l * H,
            Wr + (size_t)l * H * H, l < 2 ? 1 : 0);
    }

    mlp_kernel<<<(BATCH + 127) / 128, 256, 0, stream>>>(xh, user_ids, item_ids,
                                                        W1, b1, W2, b2, out);
}

// Round 19
// 462.089 us; speedup vs baseline: 1.2142x; 1.0302x over previous
//
#include <hip/hip_runtime.h>
#include <hip/hip_bf16.h>
#include <hip/hip_fp8.h>

#define NUM_USERS 100000
#define NUM_ITEMS 50000
#define N_NODES   150000
#define N_EDGES   4000000
#define H         64
#define BATCH     100000
#define MLP_HIDDEN 32
#define NBUCK     586          // ceil(N_NODES / 256); bucket = dst >> 8
#define BCAP      8192         // fixed bucket capacity (padded total <= ~7900)
#define ZROW      N_NODES      // index of the all-zero row appended to xh/xq

typedef unsigned short ushort_t;
typedef float f32x2 __attribute__((ext_vector_type(2)));

__device__ __forceinline__ ushort_t f2bf(float f) {   // round-to-nearest-even
    unsigned u = __float_as_uint(f);
    u = u + 0x7FFFu + ((u >> 16) & 1u);
    return (ushort_t)(u >> 16);
}
__device__ __forceinline__ unsigned pk2bf(float a, float b) {
    return (unsigned)f2bf(a) | ((unsigned)f2bf(b) << 16);
}
__device__ __forceinline__ float bfLO(unsigned u) { return __uint_as_float(u << 16); }
__device__ __forceinline__ float bfHI(unsigned u) { return __uint_as_float(u & 0xFFFF0000u); }

// ---- fp8 e4m3 pack/unpack (HW converts on gfx950; guarded fallback) -------
// NOTE: the builtin's word-select must be a LITERAL constant -> template.
#if __has_builtin(__builtin_amdgcn_cvt_pk_f32_fp8) && __has_builtin(__builtin_amdgcn_cvt_pk_fp8_f32)
#define FP8_HW 1
#endif

template <bool HI>
__device__ __forceinline__ f32x2 fp8x2_to_f32(unsigned u) {
#ifdef FP8_HW
    return __builtin_amdgcn_cvt_pk_f32_fp8(u, HI);
#else
    unsigned b0 = HI ? ((u >> 16) & 0xFFu) : (u & 0xFFu);
    unsigned b1 = HI ? ((u >> 24) & 0xFFu) : ((u >> 8) & 0xFFu);
    f32x2 r;
    {
        unsigned em = b0 & 0x7Fu;
        float mag = (em >= 8u) ? __uint_as_float((em << 20) + 0x3C000000u)
                               : (float)em * 0.001953125f;
        r.x = (b0 & 0x80u) ? -mag : mag;
    }
    {
        unsigned em = b1 & 0x7Fu;
        float mag = (em >= 8u) ? __uint_as_float((em << 20) + 0x3C000000u)
                               : (float)em * 0.001953125f;
        r.y = (b1 & 0x80u) ? -mag : mag;
    }
    return r;
#endif
}

__device__ __forceinline__ unsigned f32x4_to_fp8(float a, float b, float c, float d) {
#ifdef FP8_HW
    unsigned r = (unsigned)__builtin_amdgcn_cvt_pk_fp8_f32(a, b, 0, false);
    r = (unsigned)__builtin_amdgcn_cvt_pk_fp8_f32(c, d, (int)r, true);
    return r;
#else
    __hip_fp8_e4m3 qa(a), qb(b), qc(c), qd(d);
    return (unsigned)qa.__x | ((unsigned)qb.__x << 8) |
           ((unsigned)qc.__x << 16) | ((unsigned)qd.__x << 24);
#endif
}

// ---------------------------------------------------------------------------
// Init: xh = bf16(concat(ue, ie)), xq = fp8(concat(ue, ie)).
__global__ __launch_bounds__(256) void init_kernel(const float* __restrict__ ue,
                                                   const float* __restrict__ ie,
                                                   ushort_t* __restrict__ xh,
                                                   unsigned* __restrict__ xq) {
    int i = blockIdx.x * 256 + threadIdx.x;        // float4 index, exact grid
    const int UN4 = NUM_USERS * H / 4;
    float4 v = (i < UN4) ? ((const float4*)ue)[i] : ((const float4*)ie)[i - UN4];
    uint2 p;
    p.x = pk2bf(v.x, v.y);
    p.y = pk2bf(v.z, v.w);
    ((uint2*)xh)[i] = p;
    xq[i] = f32x4_to_fp8(v.x, v.y, v.z, v.w);
}

// ---------------------------------------------------------------------------
// CSR build pass 1: LDS-SORTED scatter into fixed-capacity buckets (proven).
// Entry packed as (src << 8) | (dst & 255).
#define SCHUNK 4096
#define SPT    (SCHUNK / 256)          // 16 edges per thread
__global__ __launch_bounds__(256) void bucket_scatter_kernel(const int* __restrict__ src,
                                                             const int* __restrict__ dst,
                                                             int* __restrict__ bucketCnt,
                                                             int* __restrict__ ebuf) {
    __shared__ int      histL[NBUCK];
    __shared__ int      startL[NBUCK];
    __shared__ int      adjL[NBUCK];
    __shared__ int      curL[NBUCK];
    __shared__ unsigned staged[SCHUNK];
    __shared__ ushort_t sbuck[SCHUNK];

    int t = threadIdx.x;
    int base = blockIdx.x * SCHUNK;
    int nst = min(SCHUNK, N_EDGES - base);

    for (int i = t; i < NBUCK; i += 256) histL[i] = 0;
    __syncthreads();

    int myd[SPT], mys[SPT];
#pragma unroll
    for (int k = 0; k < SPT; ++k) {
        int e = base + k * 256 + t;
        int d = (e < N_EDGES) ? dst[e] : -1;
        mys[k] = (e < N_EDGES) ? src[e] : 0;
        myd[k] = d;
        if (d >= 0) atomicAdd(&histL[d >> 8], 1);
    }
    __syncthreads();

    if (t < 64) {
        const int CH = (NBUCK + 63) / 64;
        int s0 = t * CH;
        int s1 = min(s0 + CH, NBUCK);
        int s = 0;
        for (int i = s0; i < s1; ++i) s += histL[i];
        int v = s;
#pragma unroll
        for (int off = 1; off < 64; off <<= 1) {
            int u = __shfl_up(v, off, 64);
            if (t >= off) v += u;
        }
        int run = v - s;
        for (int i = s0; i < s1; ++i) {
            startL[i] = run;
            run += histL[i];
        }
    }
    __syncthreads();

    for (int b = t; b < NBUCK; b += 256) {
        int h = histL[b];
        int res = h ? (b * BCAP + atomicAdd(&bucketCnt[b], h)) : 0;
        adjL[b] = res - startL[b];
        curL[b] = startL[b];
    }
    __syncthreads();

#pragma unroll
    for (int k = 0; k < SPT; ++k) {
        int d = myd[k];
        if (d >= 0) {
            int b = d >> 8;
            int pos = atomicAdd(&curL[b], 1);
            staged[pos] = ((unsigned)mys[k] << 8) | (unsigned)(d & 255);
            sbuck[pos] = (ushort_t)b;
        }
    }
    __syncthreads();

    for (int i = t; i < nst; i += 256) {
        int b = sbuck[i];
        ebuf[adjL[b] + i] = (int)staged[i];
    }
}

// CSR build pass 2: one block per bucket; segments padded to multiple of 4
// with ZROW so the gather needs no per-quad tail masking.
__global__ __launch_bounds__(1024) void bucket_build_kernel(const int* __restrict__ ebuf,
                                                            const int* __restrict__ bucketCnt,
                                                            int* __restrict__ deg,
                                                            int* __restrict__ offsets,
                                                            int* __restrict__ csr) {
    __shared__ int degL[256];
    __shared__ int scanL[256];
    __shared__ int curL[256];
    int t = threadIdx.x;
    int b = blockIdx.x;
    int nodeBase = b << 8;
    int start = b * BCAP;
    int cnt = bucketCnt[b];

    if (t < 256) degL[t] = 0;
    __syncthreads();
    for (int i = t; i < cnt; i += 1024)
        atomicAdd(&degL[ebuf[start + i] & 255], 1);
    __syncthreads();

    int v  = (t < 256) ? degL[t] : 0;
    int vp = (v + 3) & ~3;                 // padded degree
    if (t < 256) scanL[t] = vp;
    __syncthreads();
#pragma unroll
    for (int off = 1; off < 256; off <<= 1) {
        int u = (t >= off && t < 256) ? scanL[t - off] : 0;
        __syncthreads();
        if (t < 256) scanL[t] += u;
        __syncthreads();
    }

    int excl = 0;
    if (t < 256) {
        excl = scanL[t] - vp;
        int node = nodeBase + t;
        if (node < N_NODES) {
            deg[node] = v;
            offsets[node] = start + excl;
        }
        curL[t] = excl;
    }
    __syncthreads();

    for (int i = t; i < cnt; i += 1024) {
        unsigned p = (unsigned)ebuf[start + i];
        int pos = atomicAdd(&curL[p & 255u], 1);
        csr[start + pos] = (int)(p >> 8);
    }
    __syncthreads();

    if (t < 256) {
        for (int i = excl + v; i < excl + vp; ++i) csr[start + i] = ZROW;
    }
}

// ---------------------------------------------------------------------------
// Gather-mean over FP8 x: one wave per node, 4 edges per wave-instruction.
// Round 18 showed latency-bound (~2 loads in flight/wave) with VALU 59%:
// -> UNROLL 4 (4 row loads in flight) + packed f32x2 accumulate (v_pk_add).
__global__ __launch_bounds__(256, 8) void gather_mean_kernel(const unsigned* __restrict__ xq,
                                                             ushort_t* __restrict__ mean_bf,
                                                             const int* __restrict__ offsets,
                                                             const int* __restrict__ deg,
                                                             const int* __restrict__ csr) {
    int slot = threadIdx.x >> 6;
    int lane = threadIdx.x & 63;
    int q    = lane >> 4;              // edge-in-quad 0..3
    int fp   = lane & 15;              // feature-quad 0..15 (4 fp8 each)
    int node = blockIdx.x * 4 + slot;  // N_NODES % 4 == 0

    int base = offsets[node];
    int cnt  = deg[node];
    int cnt4 = (cnt + 3) & ~3;

    f32x2 aLO = (f32x2)(0.0f);         // features (0,1) of the quad
    f32x2 aHI = (f32x2)(0.0f);         // features (2,3)

    for (int c = 0; c < cnt4; c += 64) {
        int rem = cnt4 - c;                    // multiple of 4
        int sid = (lane < rem) ? csr[base + c + lane] : ZROW;
        int nq = min(64, rem) >> 2;
#define PROC(JJ) { int s = __shfl(sid, 4 * (JJ) + q, 64);                 \
        unsigned u = xq[s * 16 + fp];                                     \
        aLO += fp8x2_to_f32<false>(u);                                    \
        aHI += fp8x2_to_f32<true>(u); }
        int j = 0;
        for (; j + 4 <= nq; j += 4) { PROC(j) PROC(j + 1) PROC(j + 2) PROC(j + 3) }
        for (; j < nq; ++j) { PROC(j) }
#undef PROC
    }

    float a0 = aLO.x, a1 = aLO.y, a2 = aHI.x, a3 = aHI.y;
    a0 += __shfl_xor(a0, 16, 64); a1 += __shfl_xor(a1, 16, 64);
    a2 += __shfl_xor(a2, 16, 64); a3 += __shfl_xor(a3, 16, 64);
    a0 += __shfl_xor(a0, 32, 64); a1 += __shfl_xor(a1, 32, 64);
    a2 += __shfl_xor(a2, 32, 64); a3 += __shfl_xor(a3, 32, 64);

    if (lane < 16) {
        float rc = 1.0f / fmaxf((float)cnt, 1.0f);
        uint2 p;
        p.x = pk2bf(a0 * rc, a1 * rc);
        p.y = pk2bf(a2 * rc, a3 * rc);
        *(uint2*)&mean_bf[node * H + fp * 4] = p;
    }
}

// ---------------------------------------------------------------------------
// Transform: relu(mean @ Wl + bl + x @ Wr) -> xh (bf16, in place) and xq
// (fp8, for the next gather). Weights staged as BF16 planes in LDS.
__global__ __launch_bounds__(256) void transform_kernel(ushort_t* __restrict__ xh,
                                                        unsigned* __restrict__ xq,
                                                        const ushort_t* __restrict__ mean_bf,
                                                        const float* __restrict__ Wl,
                                                        const float* __restrict__ bl,
                                                        const float* __restrict__ Wr,
                                                        int writeQ) {
    __shared__ unsigned sWlh[H * H / 2];   // [k][h] bf16x2, 8 KB
    __shared__ unsigned sWrh[H * H / 2];   // [k][h] bf16x2, 8 KB
    __shared__ unsigned sMT[H / 2][128];   // [kpair][node] bf16x2, 16 KB
    __shared__ unsigned sXT[H / 2][128];   // [kpair][node] bf16x2, 16 KB

    int t = threadIdx.x;
    int node0 = blockIdx.x * 128;

    for (int i = t; i < H * H / 4; i += 256) {     // 1024 float4s per matrix
        float4 a = ((const float4*)Wl)[i];
        float4 b = ((const float4*)Wr)[i];
        ((uint2*)sWlh)[i] = make_uint2(pk2bf(a.x, a.y), pk2bf(a.z, a.w));
        ((uint2*)sWrh)[i] = make_uint2(pk2bf(b.x, b.y), pk2bf(b.z, b.w));
    }
#pragma unroll
    for (int it = 0; it < 8; ++it) {
        int idx = it * 256 + t;
        int n = idx & 127;
        int qd = idx >> 7;                 // uint2-quad 0..15 (k = 4qd..4qd+3)
        int node = node0 + n;
        uint2 mu = make_uint2(0u, 0u);
        uint2 xu = make_uint2(0u, 0u);
        if (node < N_NODES) {
            mu = *(const uint2*)&mean_bf[node * H + qd * 4];
            xu = *(const uint2*)&xh[node * H + qd * 4];
        }
        sMT[qd * 2][n]     = mu.x;
        sMT[qd * 2 + 1][n] = mu.y;
        sXT[qd * 2][n]     = xu.x;
        sXT[qd * 2 + 1][n] = xu.y;
    }
    __syncthreads();

    int tx = t & 7;                        // feature octet: tx*8 .. tx*8+7
    int ty = t >> 3;                       // node quad 0..31
    int nbase = node0 + ty * 4;

    f32x2 acc[4][4];                       // [node][feature-pair]
#pragma unroll
    for (int j = 0; j < 4; ++j)
#pragma unroll
        for (int p = 0; p < 4; ++p) acc[j][p] = (f32x2)(0.0f);

    for (int kp = 0; kp < H / 2; ++kp) {   // k-pairs
        uint4 mu = *(const uint4*)&sMT[kp][ty * 4];   // 4 nodes x {k0,k1}
        uint4 xu = *(const uint4*)&sXT[kp][ty * 4];
        int k0 = kp * 2;
        uint4 wl0u = *(const uint4*)&sWlh[k0 * (H / 2) + tx * 4];
        uint4 wl1u = *(const uint4*)&sWlh[(k0 + 1) * (H / 2) + tx * 4];
        uint4 wr0u = *(const uint4*)&sWrh[k0 * (H / 2) + tx * 4];
        uint4 wr1u = *(const uint4*)&sWrh[(k0 + 1) * (H / 2) + tx * 4];
        const unsigned wl0a[4] = {wl0u.x, wl0u.y, wl0u.z, wl0u.w};
        const unsigned wl1a[4] = {wl1u.x, wl1u.y, wl1u.z, wl1u.w};
        const unsigned wr0a[4] = {wr0u.x, wr0u.y, wr0u.z, wr0u.w};
        const unsigned wr1a[4] = {wr1u.x, wr1u.y, wr1u.z, wr1u.w};
        f32x2 wl0p[4], wl1p[4], wr0p[4], wr1p[4];
#pragma unroll
        for (int p = 0; p < 4; ++p) {
            wl0p[p] = (f32x2){bfLO(wl0a[p]), bfHI(wl0a[p])};
            wl1p[p] = (f32x2){bfLO(wl1a[p]), bfHI(wl1a[p])};
            wr0p[p] = (f32x2){bfLO(wr0a[p]), bfHI(wr0a[p])};
            wr1p[p] = (f32x2){bfLO(wr1a[p]), bfHI(wr1a[p])};
        }
        const unsigned mua[4] = {mu.x, mu.y, mu.z, mu.w};
        const unsigned xua[4] = {xu.x, xu.y, xu.z, xu.w};
#pragma unroll
        for (int j = 0; j < 4; ++j) {
            f32x2 m0 = (f32x2)(bfLO(mua[j]));
            f32x2 m1 = (f32x2)(bfHI(mua[j]));
            f32x2 x0 = (f32x2)(bfLO(xua[j]));
            f32x2 x1 = (f32x2)(bfHI(xua[j]));
#pragma unroll
            for (int p = 0; p < 4; ++p) {
                f32x2 a = acc[j][p];
                a = __builtin_elementwise_fma(m0, wl0p[p], a);
                a = __builtin_elementwise_fma(x0, wr0p[p], a);
                a = __builtin_elementwise_fma(m1, wl1p[p], a);
                a = __builtin_elementwise_fma(x1, wr1p[p], a);
                acc[j][p] = a;
            }
        }
    }

    float4 b0 = *(const float4*)&bl[tx * 8];
    float4 b1 = *(const float4*)&bl[tx * 8 + 4];
    f32x2 bias[4] = {{b0.x, b0.y}, {b0.z, b0.w}, {b1.x, b1.y}, {b1.z, b1.w}};
#pragma unroll
    for (int j = 0; j < 4; ++j) {
        int node = nbase + j;
        if (node < N_NODES) {
            float o[8];
#pragma unroll
            for (int p = 0; p < 4; ++p) {
                o[p * 2]     = fmaxf(acc[j][p].x + bias[p].x, 0.0f);
                o[p * 2 + 1] = fmaxf(acc[j][p].y + bias[p].y, 0.0f);
            }
            uint4 pk;
            pk.x = pk2bf(o[0], o[1]);
            pk.y = pk2bf(o[2], o[3]);
            pk.z = pk2bf(o[4], o[5]);
            pk.w = pk2bf(o[6], o[7]);
            *(uint4*)&xh[node * H + tx * 8] = pk;
            if (writeQ) {
                uint2 qk;
                qk.x = f32x4_to_fp8(o[0], o[1], o[2], o[3]);
                qk.y = f32x4_to_fp8(o[4], o[5], o[6], o[7]);
                *(uint2*)&xq[node * 16 + tx * 2] = qk;
            }
        }
    }
}

// ---------------------------------------------------------------------------
// Final MLP, register-tiled: 128 items/block, thread = 2 items x 8 hidden.
__global__ __launch_bounds__(256) void mlp_kernel(const ushort_t* __restrict__ xh,
                                                  const int* __restrict__ uids,
                                                  const int* __restrict__ iids,
                                                  const float* __restrict__ W1,
                                                  const float* __restrict__ b1,
                                                  const float* __restrict__ W2,
                                                  const float* __restrict__ b2,
                                                  float* __restrict__ out) {
    __shared__ unsigned sW1h[2 * H * MLP_HIDDEN / 2];  // [k][h] bf16x2, 8 KB
    __shared__ unsigned sPT[H][128];                   // [kpair][item] bf16x2, 32 KB
    __shared__ float    sW2f[MLP_HIDDEN];
    __shared__ float    sB1f[MLP_HIDDEN];
    __shared__ int      sUid[128];
    __shared__ int      sIid[128];

    int t = threadIdx.x;
    int item0 = blockIdx.x * 128;

    for (int i = t; i < 2 * H * MLP_HIDDEN / 4; i += 256) {   // 1024 float4s
        float4 a = ((const float4*)W1)[i];
        ((uint2*)sW1h)[i] = make_uint2(pk2bf(a.x, a.y), pk2bf(a.z, a.w));
    }
    if (t < MLP_HIDDEN) {
        sW2f[t] = W2[t];
        sB1f[t] = b1[t];
    }
    if (t < 128) {
        int g = item0 + t;
        sUid[t] = (g < BATCH) ? uids[g] : 0;
        sIid[t] = (g < BATCH) ? iids[g] : 0;
    }
    __syncthreads();

    const uint2* xr = (const uint2*)xh;
#pragma unroll
    for (int it = 0; it < 16; ++it) {
        int idx = it * 256 + t;
        int item = idx & 127;
        int chunk = idx >> 7;              // 0..31
        int half = chunk >> 4;             // 0: user, 1: item
        int fq = chunk & 15;               // uint2-quad within row
        int row = half ? (sIid[item] + NUM_USERS) : sUid[item];
        uint2 v = xr[row * 16 + fq];
        int kp0 = half * 32 + fq * 2;
        sPT[kp0][item]     = v.x;
        sPT[kp0 + 1][item] = v.y;
    }
    __syncthreads();

    int tx = t & 3;                        // hidden octet: tx*8 .. tx*8+7
    int ty = t >> 2;                       // item pair 0..63
    int ibase = item0 + ty * 2;

    f32x2 acc[2][4];                       // [item][hidden-pair]
#pragma unroll
    for (int j = 0; j < 2; ++j)
#pragma unroll
        for (int p = 0; p < 4; ++p) acc[j][p] = (f32x2)(0.0f);

    for (int kp = 0; kp < H; ++kp) {       // 64 k-pairs (2H = 128 k)
        uint2 pv = *(const uint2*)&sPT[kp][ty * 2];    // 2 items x {k0,k1}
        int k0 = kp * 2;
        uint4 w0u = *(const uint4*)&sW1h[k0 * (MLP_HIDDEN / 2) + tx * 4];
        uint4 w1u = *(const uint4*)&sW1h[(k0 + 1) * (MLP_HIDDEN / 2) + tx * 4];
        const unsigned w0a[4] = {w0u.x, w0u.y, w0u.z, w0u.w};
        const unsigned w1a[4] = {w1u.x, w1u.y, w1u.z, w1u.w};
        f32x2 w0p[4], w1p[4];
#pragma unroll
        for (int p = 0; p < 4; ++p) {
            w0p[p] = (f32x2){bfLO(w0a[p]), bfHI(w0a[p])};
            w1p[p] = (f32x2){bfLO(w1a[p]), bfHI(w1a[p])};
        }
        const unsigned pva[2] = {pv.x, pv.y};
#pragma unroll
        for (int j = 0; j < 2; ++j) {
            f32x2 m0 = (f32x2)(bfLO(pva[j]));
            f32x2 m1 = (f32x2)(bfHI(pva[j]));
#pragma unroll
            for (int p = 0; p < 4; ++p) {
                f32x2 a = acc[j][p];
                a = __builtin_elementwise_fma(m0, w0p[p], a);
                a = __builtin_elementwise_fma(m1, w1p[p], a);
                acc[j][p] = a;
            }
        }
    }

    float b2v = b2[0];
#pragma unroll
    for (int j = 0; j < 2; ++j) {
        float partial = 0.0f;
#pragma unroll
        for (int p = 0; p < 4; ++p) {
            float h0 = fmaxf(acc[j][p].x + sB1f[tx * 8 + p * 2],     0.0f);
            float h1 = fmaxf(acc[j][p].y + sB1f[tx * 8 + p * 2 + 1], 0.0f);
            partial = fmaf(h0, sW2f[tx * 8 + p * 2],     partial);
            partial = fmaf(h1, sW2f[tx * 8 + p * 2 + 1], partial);
        }
        partial += __shfl_xor(partial, 1, 64);
        partial += __shfl_xor(partial, 2, 64);
        int g = ibase + j;
        if (tx == 0 && g < BATCH)
            out[g] = fminf(fmaxf(partial + b2v, 1.0f), 5.0f);
    }
}

// ---------------------------------------------------------------------------
extern "C" void kernel_launch(void* const* d_in, const int* in_sizes, int n_in,
                              void* d_out, int out_size, void* d_ws, size_t ws_size,
                              hipStream_t stream) {
    const int*   edge_index = (const int*)d_in[0];
    const int*   user_ids   = (const int*)d_in[1];
    const int*   item_ids   = (const int*)d_in[2];
    const float* user_emb   = (const float*)d_in[3];
    const float* item_emb   = (const float*)d_in[4];
    const float* Wl         = (const float*)d_in[5];
    const float* bl         = (const float*)d_in[6];
    const float* Wr         = (const float*)d_in[7];
    const float* W1         = (const float*)d_in[8];
    const float* b1         = (const float*)d_in[9];
    const float* W2         = (const float*)d_in[10];
    const float* b2         = (const float*)d_in[11];
    float* out = (float*)d_out;

    const int* src = edge_index;
    const int* dst = edge_index + N_EDGES;

    const size_t NH = (size_t)N_NODES * H;
    ushort_t* xh      = (ushort_t*)d_ws;                 // (N_NODES+1) bf16 rows, 19.2 MB
    unsigned* xq      = (unsigned*)(xh + NH + H);        // (N_NODES+1) fp8 rows, 9.6 MB
    int* ebuf         = (int*)(xq + (NH + H) / 4);       // 19.2 MB
    ushort_t* mean_bf = (ushort_t*)ebuf;                 // bf16 overlay (CSR build done first)
    int* deg          = ebuf + (size_t)NBUCK * BCAP;     // 600 KB
    int* offsets      = deg + N_NODES;                   // 600 KB
    int* bucketCnt    = offsets + N_NODES;               // 2.3 KB
    int* csr          = bucketCnt + NBUCK;               // 19.2 MB (BCAP-strided)

    init_kernel<<<(N_NODES * H / 4) / 256, 256, 0, stream>>>(user_emb, item_emb, xh, xq);
    hipMemsetAsync(xh + NH, 0, H * sizeof(ushort_t), stream);   // zero bf16 row (ZROW)
    hipMemsetAsync(xq + NH / 4, 0, H, stream);                  // zero fp8 row (ZROW)

    // CSR build: fixed-capacity counting sort (graph identical across layers)
    hipMemsetAsync(bucketCnt, 0, NBUCK * sizeof(int), stream);
    bucket_scatter_kernel<<<(N_EDGES + SCHUNK - 1) / SCHUNK, 256, 0, stream>>>(
        src, dst, bucketCnt, ebuf);
    bucket_build_kernel<<<NBUCK, 1024, 0, stream>>>(ebuf, bucketCnt, deg, offsets, csr);

    const int TGRID = (N_NODES + 127) / 128;             // 1172
    for (int l = 0; l < 3; ++l) {
        gather_mean_kernel<<<N_NODES / 4, 256, 0, stream>>>(xq, mean_bf, offsets, deg, csr);
        transform_kernel<<<TGRID, 256, 0, stream>>>(
            xh, xq, mean_bf, Wl + (size_t)l * H * H, bl + (size_t)l * H,
            Wr + (size_t)l * H * H, l < 2 ? 1 : 0);
    }

    mlp_kernel<<<(BATCH + 127) / 128, 256, 0, stream>>>(xh, user_ids, item_ids,
                                                        W1, b1, W2, b2, out);
}